// Round 13
// baseline (144.439 us; speedup 1.0000x reference)
//
#include <hip/hip_runtime.h>

#define SEQ   2048
#define NHEADS 16
#define HDIM  64
#define HID   1024
#define ROT   32

typedef __attribute__((ext_vector_type(8))) short  short8;
typedef __attribute__((ext_vector_type(4))) float  floatx4;

__device__ __forceinline__ ushort f2bf(float f) {
    union { float f; uint u; } v; v.f = f;
    uint x = v.u;
    uint r = (x + 0x7FFFu + ((x >> 16) & 1u)) >> 16;
    return (ushort)r;
}

__device__ __forceinline__ float fexp2(float x) {
    return __builtin_amdgcn_exp2f(x);     // v_exp_f32 directly
}

__device__ __forceinline__ floatx4 mfma_bf16(short8 a, short8 b, floatx4 c) {
    return __builtin_amdgcn_mfma_f32_16x16x32_bf16(a, b, c, 0, 0, 0);
}

__device__ __forceinline__ void gload16(const ushort* g, ushort* l) {
    __builtin_amdgcn_global_load_lds(
        (const __attribute__((address_space(1))) void*)g,
        (__attribute__((address_space(3))) void*)l, 16, 0, 0);
}

// ---------------------------------------------------------------------------
// Pre-pass A: fp32 -> bf16 elementwise (hidden)
// ---------------------------------------------------------------------------
__global__ __launch_bounds__(256) void convert_bf16_kernel(
    const float* __restrict__ src, ushort* __restrict__ dst, int n)
{
    int i = (blockIdx.x * 256 + threadIdx.x) * 8;
    if (i >= n) return;
    float4 a = *(const float4*)(src + i);
    float4 b = *(const float4*)(src + i + 4);
    short8 v;
    v[0] = (short)f2bf(a.x); v[1] = (short)f2bf(a.y);
    v[2] = (short)f2bf(a.z); v[3] = (short)f2bf(a.w);
    v[4] = (short)f2bf(b.x); v[5] = (short)f2bf(b.y);
    v[6] = (short)f2bf(b.z); v[7] = (short)f2bf(b.w);
    *(short8*)(dst + i) = v;
}

// ---------------------------------------------------------------------------
// Pre-pass B: fp32 (K,N) -> bf16 (N,K) transpose-convert. Tile 64x64.
// ---------------------------------------------------------------------------
__global__ __launch_bounds__(256) void transpose_bf16_kernel(
    const float* __restrict__ src, ushort* __restrict__ dst, int K, int N)
{
    __shared__ ushort Tl[64 * 68];
    const int k0 = blockIdx.y * 64, n0 = blockIdx.x * 64;
    const int tid = threadIdx.x;
    #pragma unroll
    for (int i = 0; i < 4; i++) {
        int lin = tid + 256 * i;
        int row = lin >> 4;
        int c4  = (lin & 15) * 4;
        float4 v = *(const float4*)(src + (size_t)(k0 + row) * N + n0 + c4);
        uint2 u;
        u.x = (uint)f2bf(v.x) | ((uint)f2bf(v.y) << 16);
        u.y = (uint)f2bf(v.z) | ((uint)f2bf(v.w) << 16);
        *(uint2*)&Tl[row * 68 + c4] = u;
    }
    __syncthreads();
    #pragma unroll
    for (int j = 0; j < 2; j++) {
        int lin = tid + 256 * j;
        int n = lin >> 3, c = lin & 7;
        short8 v;
        #pragma unroll
        for (int u = 0; u < 8; u++) v[u] = (short)Tl[(c * 8 + u) * 68 + n];
        *(short8*)(dst + (size_t)(n0 + n) * K + k0 + c * 8) = v;
    }
}

// ---------------------------------------------------------------------------
// Kernel 1: qkv = hidden @ w_qkv (M=4096, N=3072, K=1024) bf16 inputs.
// 256x256 tile, grid 192 = 1 block/CU (wall = single-block time; depth-2
// 3-buffer prefetch is FREE since occupancy is grid-limited). BK=32,
// counted vmcnt(4): tile t+2's loads stay in flight across the barrier.
// 8 waves (2m x 4n), per-wave acc[8][4]. NO launch_bounds min-occupancy
// arg (r11 lesson: it caps VGPRs as CUDA min-blocks semantics).
// Fused RoPE + head split. Q pre-scaled by 0.125*log2(e).
// Q,K (b,h,s,d); V (b,h,d,s).
// ---------------------------------------------------------------------------
__global__ __launch_bounds__(512) void qkv_rope_kernel(
    const ushort* __restrict__ hbf,     // (4096,1024) bf16
    const ushort* __restrict__ wqkvT,   // (3072,1024) bf16 (N,K)
    ushort* __restrict__ Qb, ushort* __restrict__ Kb, ushort* __restrict__ Vb)
{
    __shared__ ushort Al[3 * 8192];     // 3 bufs x (256 rows x 32 k)
    __shared__ ushort Bl[3 * 8192];
    const int tid  = threadIdx.x;
    const int lane = tid & 63;
    const int wv   = tid >> 6;          // 0..7
    const int g    = lane >> 4;
    const int l15  = lane & 15;

    // XCD remap over 16(m) x 12(n) tile grid: each XCD owns 4(m) x 6(n).
    const int lin  = blockIdx.x + 12 * blockIdx.y;  // 0..191
    const int xcd  = lin & 7;
    const int slot = lin >> 3;                      // 0..23
    const int cxi  = xcd & 1, cyi = xcd >> 1;       // 2(n) x 4(m) chunks
    const int sx   = slot % 6, sy = slot / 6;       // 6(n) x 4(m)
    const int n0   = (cxi * 6 + sx) * 256;
    const int m0   = (cyi * 4 + sy) * 256;

    const int wr = (wv >> 2) * 128;     // 0,128   (2 m-waves)
    const int wc = (wv & 3) * 64;       // 0..192  (4 n-waves)

    floatx4 acc[8][4];
    #pragma unroll
    for (int a = 0; a < 8; a++)
        #pragma unroll
        for (int bq = 0; bq < 4; bq++)
            acc[a][bq] = floatx4{0.f, 0.f, 0.f, 0.f};

    // staging: 1024 16B-chunks per tensor per tile = 2 chunks/thread each.
    // thread t owns (row = t>>2, cc = t&3) and (row+128, cc).
    const ushort* ga = hbf   + (size_t)(m0 + (tid >> 2)) * 1024 + (tid & 3) * 8;
    const ushort* gb = wqkvT + (size_t)(n0 + (tid >> 2)) * 1024 + (tid & 3) * 8;
    const int lofs = tid * 8;           // ushort offset of this thread's chunk

    auto stage = [&](int t, int obuf) {
        const int k0 = t * 32;
        gload16(ga + k0,                &Al[obuf + lofs]);
        gload16(ga + k0 + 128 * 1024,   &Al[obuf + lofs + 4096]);
        gload16(gb + k0,                &Bl[obuf + lofs]);
        gload16(gb + k0 + 128 * 1024,   &Bl[obuf + lofs + 4096]);
    };

    int o0 = 0, o1 = 8192, o2 = 16384;
    stage(0, o0);
    stage(1, o1);
    asm volatile("s_waitcnt vmcnt(4)" ::: "memory");   // tile 0 resident
    __builtin_amdgcn_s_barrier();

    for (int it = 0; it < 32; it++) {
        const bool pre = (it + 2 < 32);
        if (pre) stage(it + 2, o2);
        short8 af[8], bfr[4];
        #pragma unroll
        for (int fm = 0; fm < 8; fm++)
            af[fm] = *(const short8*)&Al[o0 + (wr + fm * 16 + l15) * 32 + g * 8];
        #pragma unroll
        for (int fn = 0; fn < 4; fn++)
            bfr[fn] = *(const short8*)&Bl[o0 + (wc + fn * 16 + l15) * 32 + g * 8];
        #pragma unroll
        for (int fm = 0; fm < 8; fm++)
            #pragma unroll
            for (int fn = 0; fn < 4; fn++)
                acc[fm][fn] = mfma_bf16(af[fm], bfr[fn], acc[fm][fn]);
        // complete tile it+1 (oldest 4 loads); tile it+2's stay in flight
        if (pre) asm volatile("s_waitcnt vmcnt(4)" ::: "memory");
        else     asm volatile("s_waitcnt vmcnt(0)" ::: "memory");
        __builtin_amdgcn_s_barrier();
        int tmp = o0; o0 = o1; o1 = o2; o2 = tmp;
    }

    // epilogue: RoPE + head-split scatter
    #pragma unroll
    for (int fn = 0; fn < 4; fn++) {
        const int c    = n0 + wc + fn * 16 + l15;
        const int mp   = c / 384;
        const int rem  = c - mp * 384;
        const int tsel = rem >> 7;                    // 0=q 1=k 2=v
        const int j    = (rem >> 6) & 1;
        const int d    = rem & 63;
        const int head = mp * 2 + j;
        ushort* basep = (tsel == 0) ? Qb : (tsel == 1) ? Kb : Vb;
        const bool rope = (tsel < 2) && (d < ROT);
        // Q carries 1/sqrt(64) * log2(e) so attention uses exp2 directly
        const float qscale = (tsel == 0) ? 0.18033688011112042f : 1.0f;
        float freq = 0.f;
        if (rope) {
            freq = exp2f((float)(d >> 1) * -0.830482023721841f);
        }
        #pragma unroll
        for (int fm = 0; fm < 8; fm++) {
            #pragma unroll
            for (int r = 0; r < 4; r++) {
                int row = m0 + wr + fm * 16 + g * 4 + r;
                int bb  = row >> 11;
                int s   = row & 2047;
                float val = acc[fm][fn][r];
                float pv  = __shfl_xor(val, 1, 64);
                float outv = val;
                if (rope) {
                    float ang = (float)s * freq;
                    float sn, cs;
                    __sincosf(ang, &sn, &cs);
                    outv = ((d & 1) == 0) ? (val * cs - pv * sn)
                                          : (val * cs + pv * sn);
                }
                outv *= qscale;
                size_t off;
                if (tsel == 2)
                    off = ((size_t)(bb * NHEADS + head) * HDIM + d) * SEQ + s;
                else
                    off = ((size_t)(bb * NHEADS + head) * SEQ + s) * HDIM + d;
                basep[off] = f2bf(outv);
            }
        }
    }
}

// ---------------------------------------------------------------------------
// Kernel 2: flash attention, causal. 512 threads = 8 waves x 16 q-rows
// (Q tile 128), KV tiles 64. Complementary-qb pairing; 2-deep register
// prefetch + LDS double-buffer; exp2-domain softmax with per-lane defer-max
// (cross-lane reduces only on rescale) and epilogue-deferred l-sum.
// ---------------------------------------------------------------------------
__global__ __launch_bounds__(512, 4) void attn_kernel(
    const ushort* __restrict__ Qb, const ushort* __restrict__ Kb,
    const ushort* __restrict__ Vb, ushort* __restrict__ attn)
{
    __shared__ ushort Kl[2][64 * 72];      // [key][d], stride 72
    __shared__ ushort Vt[2][64 * 72];      // [d][key], stride 72

    const int tid  = threadIdx.x;
    const int lane = tid & 63;
    const int wv   = tid >> 6;             // 0..7
    const int g    = lane >> 4;
    const int l15  = lane & 15;

    const int l    = blockIdx.x + 16 * blockIdx.y + 256 * blockIdx.z;
    const int half = l >> 8;
    const int xx   = l & 15;
    const int hh   = (l >> 4) & 15;
    const int qb   = half ? xx : 15 - xx;
    const int bb   = half;

    const int q0 = qb * 128;
    const int wq = wv * 16;
    const size_t kvbase = (size_t)(bb * NHEADS + hh) * SEQ * HDIM;

    const int srow = tid >> 3;             // 0..63 staging row
    const int sch  = (tid & 7) * 8;        // staging col (ushort)

    short8 qreg[2];
    #pragma unroll
    for (int ks = 0; ks < 2; ks++)
        qreg[ks] = *(const short8*)(Qb + kvbase +
            (size_t)(q0 + wq + l15) * HDIM + ks * 32 + g * 8);

    float m = -__builtin_inff();
    float lsum = 0.f;                      // per-lane partial (16 keys/row)
    floatx4 of[4];
    #pragma unroll
    for (int df = 0; df < 4; df++) of[df] = floatx4{0.f, 0.f, 0.f, 0.f};

    const int nt = 2 * qb + 2;             // always even

    auto load_tile = [&](int tt, short8& kr, short8& vr) {
        const int kv = tt * 64;
        kr = *(const short8*)(Kb + kvbase + (size_t)(kv + srow) * HDIM + sch);
        vr = *(const short8*)(Vb + kvbase + (size_t)srow * SEQ + kv + sch);
    };
    auto write_tile = [&](int buf, short8& kr, short8& vr) {
        *(short8*)&Kl[buf][srow * 72 + sch] = kr;
        *(short8*)&Vt[buf][srow * 72 + sch] = vr;
    };
    auto compute_tile = [&](int t, const ushort* Kc, const ushort* Vc) {
        const int kv0 = t * 64;
        if (kv0 > q0 + wq + 15) return;    // fully-masked for this wave
        // QK^T (swapped): sf[kf], lane l15 = q-row, key = kv0 + kf*16 + g*4 + r
        floatx4 sf[4];
        __builtin_amdgcn_s_setprio(1);
        #pragma unroll
        for (int kf = 0; kf < 4; kf++) {
            short8 kr0 = *(const short8*)&Kc[(kf * 16 + l15) * 72 + g * 8];
            short8 kr1 = *(const short8*)&Kc[(kf * 16 + l15) * 72 + 32 + g * 8];
            floatx4 s = floatx4{0.f, 0.f, 0.f, 0.f};
            s = mfma_bf16(kr0, qreg[0], s);
            s = mfma_bf16(kr1, qreg[1], s);
            sf[kf] = s;
        }
        __builtin_amdgcn_s_setprio(0);

        const bool diag = (kv0 + 63 > q0 + wq);   // wave-uniform
        const int qg = q0 + wq + l15;
        float tmax = -__builtin_inff();
        if (diag) {
            #pragma unroll
            for (int kf = 0; kf < 4; kf++) {
                #pragma unroll
                for (int r = 0; r < 4; r++) {
                    int key = kv0 + kf * 16 + g * 4 + r;
                    float x = sf[kf][r];
                    if (key > qg) x = -1e9f;
                    sf[kf][r] = x;
                    tmax = fmaxf(tmax, x);
                }
            }
        } else {
            #pragma unroll
            for (int kf = 0; kf < 4; kf++)
                #pragma unroll
                for (int r = 0; r < 4; r++)
                    tmax = fmaxf(tmax, sf[kf][r]);
        }
        // per-lane defer-max: no cross-lane traffic in the common case
        if (!__all(tmax <= m + 8.0f)) {
            tmax = fmaxf(tmax, __shfl_xor(tmax, 16, 64));
            tmax = fmaxf(tmax, __shfl_xor(tmax, 32, 64));
            float mn = fmaxf(m, tmax);
            float f  = fexp2(m - mn);
            m = mn;
            lsum *= f;
            #pragma unroll
            for (int r = 0; r < 4; r++) {
                float fr = __shfl(f, g * 4 + r, 64);
                #pragma unroll
                for (int df = 0; df < 4; df++)
                    of[df][r] *= fr;
            }
        }
        float rs = 0.f;
        #pragma unroll
        for (int kf = 0; kf < 4; kf++) {
            #pragma unroll
            for (int r = 0; r < 4; r++) {
                float p = fexp2(sf[kf][r] - m);
                sf[kf][r] = p;
                rs += p;
            }
        }
        lsum += rs;
        // pack P into lane-local A-frags via v_cvt_pk_bf16_f32
        short8 pa[2];
        #pragma unroll
        for (int ks = 0; ks < 2; ks++) {
            union { short8 s; uint u[4]; } pu;
            #pragma unroll
            for (int w = 0; w < 4; w++) {
                const int kf = 2 * ks + (w >> 1);
                float lo = sf[kf][(w & 1) * 2 + 0];
                float hi = sf[kf][(w & 1) * 2 + 1];
                asm("v_cvt_pk_bf16_f32 %0, %1, %2"
                    : "=v"(pu.u[w]) : "v"(lo), "v"(hi));
            }
            pa[ks] = pu.s;
        }
        // PV
        __builtin_amdgcn_s_setprio(1);
        #pragma unroll
        for (int df = 0; df < 4; df++) {
            #pragma unroll
            for (int ks = 0; ks < 2; ks++) {
                const int vb = (df * 16 + l15) * 72 + ks * 32 + g * 4;
                uint2 v0 = *(const uint2*)&Vc[vb];
                uint2 v1 = *(const uint2*)&Vc[vb + 16];
                union { short8 s; uint4 u; } vv;
                vv.u.x = v0.x; vv.u.y = v0.y; vv.u.z = v1.x; vv.u.w = v1.y;
                of[df] = mfma_bf16(pa[ks], vv.s, of[df]);
            }
        }
        __builtin_amdgcn_s_setprio(0);
    };

    short8 kA, vA, kB, vB;
    load_tile(0, kA, vA);
    if (nt > 1) load_tile(1, kB, vB);
    write_tile(0, kA, vA);
    __syncthreads();

    for (int t = 0; t < nt; t += 2) {
        if (t + 2 < nt) load_tile(t + 2, kA, vA);
        compute_tile(t, Kl[0], Vt[0]);
        write_tile(1, kB, vB);
        __syncthreads();
        if (t + 3 < nt) load_tile(t + 3, kB, vB);
        compute_tile(t + 1, Kl[1], Vt[1]);
        if (t + 2 < nt) write_tile(0, kA, vA);
        __syncthreads();
    }

    // epilogue: reduce l across g-lanes once, O /= l, store attn (b,s,H) bf16
    lsum += __shfl_xor(lsum, 16, 64);
    lsum += __shfl_xor(lsum, 32, 64);
    #pragma unroll
    for (int r = 0; r < 4; r++) {
        float lr = __shfl(lsum, g * 4 + r, 64);
        float inv = 1.0f / lr;
        int q = q0 + wq + g * 4 + r;
        #pragma unroll
        for (int df = 0; df < 4; df++)
            attn[((size_t)bb * SEQ + q) * HID + hh * 64 + df * 16 + l15] =
                f2bf(of[df][r] * inv);
    }
}

// ---------------------------------------------------------------------------
// Kernel 3: out = attn @ w_out (M=4096, N=1024, K=1024), 2-phase pipelined
// double-buffer (round-9 form), fp32 output.
// ---------------------------------------------------------------------------
__global__ __launch_bounds__(256) void out_proj_kernel(
    const ushort* __restrict__ attn,    // (4096,1024) bf16
    const ushort* __restrict__ woutT,   // (1024,1024) bf16 (N,K)
    float* __restrict__ out)
{
    __shared__ ushort Al[2][128 * 32];
    __shared__ ushort Bl[2][128 * 32];
    const int tid  = threadIdx.x;
    const int lane = tid & 63;
    const int wv   = tid >> 6;
    const int g    = lane >> 4;
    const int l15  = lane & 15;

    const int lin  = blockIdx.x + 8 * blockIdx.y;   // 0..255
    const int xcd  = lin & 7;
    const int slot = lin >> 3;                      // 0..31
    const int cxi  = xcd & 1, cyi = xcd >> 1;
    const int sx   = slot & 3, sy = slot >> 2;      // 4x8
    const int n0   = (cxi * 4 + sx) * 128;
    const int m0   = (cyi * 8 + sy) * 128;

    const int wr = (wv >> 1) * 64;
    const int wc = (wv & 1) * 64;
    const int rowl = lane >> 2;
    const int kcol = (lane & 3) * 8;

    floatx4 acc[4][4];
    #pragma unroll
    for (int a = 0; a < 4; a++)
        #pragma unroll
        for (int bq = 0; bq < 4; bq++)
            acc[a][bq] = floatx4{0.f, 0.f, 0.f, 0.f};

    const ushort* ga = attn  + (size_t)(m0 + wv * 32 + rowl) * 1024 + kcol;
    const ushort* gb = woutT + (size_t)(n0 + wv * 32 + rowl) * 1024 + kcol;
    const int lofs = wv * 1024;

    gload16(ga,             &Al[0][lofs]);
    gload16(ga + 16 * 1024, &Al[0][lofs + 512]);
    gload16(gb,             &Bl[0][lofs]);
    gload16(gb + 16 * 1024, &Bl[0][lofs + 512]);
    asm volatile("s_waitcnt vmcnt(0)" ::: "memory");
    __builtin_amdgcn_s_barrier();

    for (int it = 0; it < 32; it++) {
        const int cur = it & 1;
        if (it + 1 < 32) {
            const int k0 = (it + 1) * 32;
            const int nxt = cur ^ 1;
            gload16(ga + k0,             &Al[nxt][lofs]);
            gload16(ga + k0 + 16 * 1024, &Al[nxt][lofs + 512]);
            gload16(gb + k0,             &Bl[nxt][lofs]);
            gload16(gb + k0 + 16 * 1024, &Bl[nxt][lofs + 512]);
        }
        short8 af[4], bfr[4];
        #pragma unroll
        for (int fm = 0; fm < 4; fm++)
            af[fm] = *(const short8*)&Al[cur][(wr + fm * 16 + l15) * 32 + g * 8];
        #pragma unroll
        for (int fn = 0; fn < 4; fn++)
            bfr[fn] = *(const short8*)&Bl[cur][(wc + fn * 16 + l15) * 32 + g * 8];
        #pragma unroll
        for (int fm = 0; fm < 4; fm++)
            #pragma unroll
            for (int fn = 0; fn < 4; fn++)
                acc[fm][fn] = mfma_bf16(af[fm], bfr[fn], acc[fm][fn]);
        asm volatile("s_waitcnt vmcnt(0)" ::: "memory");
        __builtin_amdgcn_s_barrier();
    }
    #pragma unroll
    for (int fm = 0; fm < 4; fm++)
        #pragma unroll
        for (int fn = 0; fn < 4; fn++)
            #pragma unroll
            for (int r = 0; r < 4; r++) {
                int row = m0 + wr + fm * 16 + g * 4 + r;
                int col = n0 + wc + fn * 16 + l15;
                out[(size_t)row * 1024 + col] = acc[fm][fn][r];
            }
}

// ---------------------------------------------------------------------------
extern "C" void kernel_launch(void* const* d_in, const int* in_sizes, int n_in,
                              void* d_out, int out_size, void* d_ws, size_t ws_size,
                              hipStream_t stream)
{
    const float* hidden = (const float*)d_in[0];
    const float* wqkv   = (const float*)d_in[1];
    const float* wout   = (const float*)d_in[2];
    float* out = (float*)d_out;

    const size_t NELEM = (size_t)2 * SEQ * HID;   // 4,194,304
    ushort* Qb    = (ushort*)d_ws;
    ushort* Kb    = Qb + NELEM;
    ushort* Vb    = Kb + NELEM;
    ushort* hbf   = Vb + NELEM;                   // hidden bf16; later reused as attn
    ushort* wqkvT = hbf + NELEM;                  // 3072*1024
    ushort* woutT = wqkvT + (size_t)3072 * 1024;  // 1024*1024
    ushort* attnb = hbf;                          // alias: lifetime disjoint

    convert_bf16_kernel<<<2048, 256, 0, stream>>>(hidden, hbf, (int)NELEM);
    transpose_bf16_kernel<<<dim3(48, 16), 256, 0, stream>>>(wqkv, wqkvT, 1024, 3072);
    transpose_bf16_kernel<<<dim3(16, 16), 256, 0, stream>>>(wout, woutT, 1024, 1024);
    qkv_rope_kernel<<<dim3(12, 16), 512, 0, stream>>>(hbf, wqkvT, Qb, Kb, Vb);
    attn_kernel<<<dim3(16, NHEADS, 2), 512, 0, stream>>>(Qb, Kb, Vb, attnb);
    out_proj_kernel<<<dim3(8, 32), 256, 0, stream>>>(attnb, woutT, out);
}

// Round 14
// 133.357 us; speedup vs baseline: 1.0831x; 1.0831x over previous
//
#include <hip/hip_runtime.h>

#define SEQ   2048
#define NHEADS 16
#define HDIM  64
#define HID   1024
#define ROT   32

typedef __attribute__((ext_vector_type(8))) short  short8;
typedef __attribute__((ext_vector_type(4))) float  floatx4;

__device__ __forceinline__ ushort f2bf(float f) {
    union { float f; uint u; } v; v.f = f;
    uint x = v.u;
    uint r = (x + 0x7FFFu + ((x >> 16) & 1u)) >> 16;
    return (ushort)r;
}

__device__ __forceinline__ float fexp2(float x) {
    return __builtin_amdgcn_exp2f(x);     // v_exp_f32 directly
}

__device__ __forceinline__ floatx4 mfma_bf16(short8 a, short8 b, floatx4 c) {
    return __builtin_amdgcn_mfma_f32_16x16x32_bf16(a, b, c, 0, 0, 0);
}

__device__ __forceinline__ void gload16(const ushort* g, ushort* l) {
    __builtin_amdgcn_global_load_lds(
        (const __attribute__((address_space(1))) void*)g,
        (__attribute__((address_space(3))) void*)l, 16, 0, 0);
}

// ---------------------------------------------------------------------------
// Pre-pass A: fp32 -> bf16 elementwise (hidden)
// ---------------------------------------------------------------------------
__global__ __launch_bounds__(256) void convert_bf16_kernel(
    const float* __restrict__ src, ushort* __restrict__ dst, int n)
{
    int i = (blockIdx.x * 256 + threadIdx.x) * 8;
    if (i >= n) return;
    float4 a = *(const float4*)(src + i);
    float4 b = *(const float4*)(src + i + 4);
    short8 v;
    v[0] = (short)f2bf(a.x); v[1] = (short)f2bf(a.y);
    v[2] = (short)f2bf(a.z); v[3] = (short)f2bf(a.w);
    v[4] = (short)f2bf(b.x); v[5] = (short)f2bf(b.y);
    v[6] = (short)f2bf(b.z); v[7] = (short)f2bf(b.w);
    *(short8*)(dst + i) = v;
}

// ---------------------------------------------------------------------------
// Pre-pass B: fp32 (K,N) -> bf16 (N,K) transpose-convert. Tile 64x64.
// ---------------------------------------------------------------------------
__global__ __launch_bounds__(256) void transpose_bf16_kernel(
    const float* __restrict__ src, ushort* __restrict__ dst, int K, int N)
{
    __shared__ ushort Tl[64 * 68];
    const int k0 = blockIdx.y * 64, n0 = blockIdx.x * 64;
    const int tid = threadIdx.x;
    #pragma unroll
    for (int i = 0; i < 4; i++) {
        int lin = tid + 256 * i;
        int row = lin >> 4;
        int c4  = (lin & 15) * 4;
        float4 v = *(const float4*)(src + (size_t)(k0 + row) * N + n0 + c4);
        uint2 u;
        u.x = (uint)f2bf(v.x) | ((uint)f2bf(v.y) << 16);
        u.y = (uint)f2bf(v.z) | ((uint)f2bf(v.w) << 16);
        *(uint2*)&Tl[row * 68 + c4] = u;
    }
    __syncthreads();
    #pragma unroll
    for (int j = 0; j < 2; j++) {
        int lin = tid + 256 * j;
        int n = lin >> 3, c = lin & 7;
        short8 v;
        #pragma unroll
        for (int u = 0; u < 8; u++) v[u] = (short)Tl[(c * 8 + u) * 68 + n];
        *(short8*)(dst + (size_t)(n0 + n) * K + k0 + c * 8) = v;
    }
}

// ---------------------------------------------------------------------------
// Kernel 1: qkv = hidden @ w_qkv (M=4096, N=3072, K=1024) bf16 inputs.
// 256x256 tile, 1024 threads = 16 waves (4m x 4n of 64x64) -> per-thread
// acc[4][4] (r12's register geometry: VGPR ~56, 4 waves/SIMD TLP; r13's
// 512-thr variant starved at 1 wave/SIMD). Grid 192 = 1 block/CU.
// Bytes/FLOP 7.6 vs r12's 11.4. r12 2-phase pipelined double-buffer.
// Fused RoPE + head split. Q pre-scaled by 0.125*log2(e).
// Q,K (b,h,s,d); V (b,h,d,s).
// ---------------------------------------------------------------------------
__global__ __launch_bounds__(1024) void qkv_rope_kernel(
    const ushort* __restrict__ hbf,     // (4096,1024) bf16
    const ushort* __restrict__ wqkvT,   // (3072,1024) bf16 (N,K)
    ushort* __restrict__ Qb, ushort* __restrict__ Kb, ushort* __restrict__ Vb)
{
    __shared__ ushort Al[2][8192];      // 256 rows x 32 k
    __shared__ ushort Bl[2][8192];
    const int tid  = threadIdx.x;
    const int lane = tid & 63;
    const int wv   = tid >> 6;          // 0..15
    const int g    = lane >> 4;
    const int l15  = lane & 15;

    // XCD remap over 16(m) x 12(n) tile grid: each XCD owns 4(m) x 6(n)
    // (A-stripe 2MB + B-stripe 3MB ~ L2-resident).
    const int lin  = blockIdx.x + 12 * blockIdx.y;  // 0..191
    const int xcd  = lin & 7;
    const int slot = lin >> 3;                      // 0..23
    const int cxi  = xcd & 1, cyi = xcd >> 1;       // 2(n) x 4(m) chunks
    const int sx   = slot % 6, sy = slot / 6;       // 6(n) x 4(m)
    const int n0   = (cxi * 6 + sx) * 256;
    const int m0   = (cyi * 4 + sy) * 256;

    const int wr = (wv >> 2) * 64;      // 0..192 (4 m-waves)
    const int wc = (wv & 3) * 64;       // 0..192 (4 n-waves)

    floatx4 acc[4][4];
    #pragma unroll
    for (int a = 0; a < 4; a++)
        #pragma unroll
        for (int bq = 0; bq < 4; bq++)
            acc[a][bq] = floatx4{0.f, 0.f, 0.f, 0.f};

    // staging: thread t owns A-row t>>2 chunk t&3, same for B. 1 load each.
    const ushort* ga = hbf   + (size_t)(m0 + (tid >> 2)) * 1024 + (tid & 3) * 8;
    const ushort* gb = wqkvT + (size_t)(n0 + (tid >> 2)) * 1024 + (tid & 3) * 8;
    const int lofs = tid * 8;           // ushort offset (16B per thread)

    auto stage = [&](int t, int buf) {
        const int k0 = t * 32;
        gload16(ga + k0, &Al[buf][lofs]);
        gload16(gb + k0, &Bl[buf][lofs]);
    };

    stage(0, 0);
    asm volatile("s_waitcnt vmcnt(0)" ::: "memory");
    __builtin_amdgcn_s_barrier();

    for (int it = 0; it < 32; it++) {
        const int cur = it & 1;
        if (it + 1 < 32) stage(it + 1, cur ^ 1);
        short8 af[4], bfr[4];
        #pragma unroll
        for (int fm = 0; fm < 4; fm++)
            af[fm] = *(const short8*)&Al[cur][(wr + fm * 16 + l15) * 32 + g * 8];
        #pragma unroll
        for (int fn = 0; fn < 4; fn++)
            bfr[fn] = *(const short8*)&Bl[cur][(wc + fn * 16 + l15) * 32 + g * 8];
        #pragma unroll
        for (int fm = 0; fm < 4; fm++)
            #pragma unroll
            for (int fn = 0; fn < 4; fn++)
                acc[fm][fn] = mfma_bf16(af[fm], bfr[fn], acc[fm][fn]);
        asm volatile("s_waitcnt vmcnt(0)" ::: "memory");
        __builtin_amdgcn_s_barrier();
    }

    // epilogue: RoPE + head-split scatter (per-wave 64x64 at (wr,wc))
    #pragma unroll
    for (int fn = 0; fn < 4; fn++) {
        const int c    = n0 + wc + fn * 16 + l15;
        const int mp   = c / 384;
        const int rem  = c - mp * 384;
        const int tsel = rem >> 7;                    // 0=q 1=k 2=v
        const int j    = (rem >> 6) & 1;
        const int d    = rem & 63;
        const int head = mp * 2 + j;
        ushort* basep = (tsel == 0) ? Qb : (tsel == 1) ? Kb : Vb;
        const bool rope = (tsel < 2) && (d < ROT);
        // Q carries 1/sqrt(64) * log2(e) so attention uses exp2 directly
        const float qscale = (tsel == 0) ? 0.18033688011112042f : 1.0f;
        float freq = 0.f;
        if (rope) {
            freq = exp2f((float)(d >> 1) * -0.830482023721841f);
        }
        #pragma unroll
        for (int fm = 0; fm < 4; fm++) {
            #pragma unroll
            for (int r = 0; r < 4; r++) {
                int row = m0 + wr + fm * 16 + g * 4 + r;
                int bb  = row >> 11;
                int s   = row & 2047;
                float val = acc[fm][fn][r];
                float pv  = __shfl_xor(val, 1, 64);
                float outv = val;
                if (rope) {
                    float ang = (float)s * freq;
                    float sn, cs;
                    __sincosf(ang, &sn, &cs);
                    outv = ((d & 1) == 0) ? (val * cs - pv * sn)
                                          : (val * cs + pv * sn);
                }
                outv *= qscale;
                size_t off;
                if (tsel == 2)
                    off = ((size_t)(bb * NHEADS + head) * HDIM + d) * SEQ + s;
                else
                    off = ((size_t)(bb * NHEADS + head) * SEQ + s) * HDIM + d;
                basep[off] = f2bf(outv);
            }
        }
    }
}

// ---------------------------------------------------------------------------
// Kernel 2: flash attention, causal. 512 threads = 8 waves x 16 q-rows
// (Q tile 128), KV tiles 64. Complementary-qb pairing; 2-deep register
// prefetch + LDS double-buffer; exp2-domain softmax with per-lane defer-max
// (cross-lane reduces only on rescale) and epilogue-deferred l-sum.
// ---------------------------------------------------------------------------
__global__ __launch_bounds__(512, 4) void attn_kernel(
    const ushort* __restrict__ Qb, const ushort* __restrict__ Kb,
    const ushort* __restrict__ Vb, ushort* __restrict__ attn)
{
    __shared__ ushort Kl[2][64 * 72];      // [key][d], stride 72
    __shared__ ushort Vt[2][64 * 72];      // [d][key], stride 72

    const int tid  = threadIdx.x;
    const int lane = tid & 63;
    const int wv   = tid >> 6;             // 0..7
    const int g    = lane >> 4;
    const int l15  = lane & 15;

    const int l    = blockIdx.x + 16 * blockIdx.y + 256 * blockIdx.z;
    const int half = l >> 8;
    const int xx   = l & 15;
    const int hh   = (l >> 4) & 15;
    const int qb   = half ? xx : 15 - xx;
    const int bb   = half;

    const int q0 = qb * 128;
    const int wq = wv * 16;
    const size_t kvbase = (size_t)(bb * NHEADS + hh) * SEQ * HDIM;

    const int srow = tid >> 3;             // 0..63 staging row
    const int sch  = (tid & 7) * 8;        // staging col (ushort)

    short8 qreg[2];
    #pragma unroll
    for (int ks = 0; ks < 2; ks++)
        qreg[ks] = *(const short8*)(Qb + kvbase +
            (size_t)(q0 + wq + l15) * HDIM + ks * 32 + g * 8);

    float m = -__builtin_inff();
    float lsum = 0.f;                      // per-lane partial (16 keys/row)
    floatx4 of[4];
    #pragma unroll
    for (int df = 0; df < 4; df++) of[df] = floatx4{0.f, 0.f, 0.f, 0.f};

    const int nt = 2 * qb + 2;             // always even

    auto load_tile = [&](int tt, short8& kr, short8& vr) {
        const int kv = tt * 64;
        kr = *(const short8*)(Kb + kvbase + (size_t)(kv + srow) * HDIM + sch);
        vr = *(const short8*)(Vb + kvbase + (size_t)srow * SEQ + kv + sch);
    };
    auto write_tile = [&](int buf, short8& kr, short8& vr) {
        *(short8*)&Kl[buf][srow * 72 + sch] = kr;
        *(short8*)&Vt[buf][srow * 72 + sch] = vr;
    };
    auto compute_tile = [&](int t, const ushort* Kc, const ushort* Vc) {
        const int kv0 = t * 64;
        if (kv0 > q0 + wq + 15) return;    // fully-masked for this wave
        // QK^T (swapped): sf[kf], lane l15 = q-row, key = kv0 + kf*16 + g*4 + r
        floatx4 sf[4];
        __builtin_amdgcn_s_setprio(1);
        #pragma unroll
        for (int kf = 0; kf < 4; kf++) {
            short8 kr0 = *(const short8*)&Kc[(kf * 16 + l15) * 72 + g * 8];
            short8 kr1 = *(const short8*)&Kc[(kf * 16 + l15) * 72 + 32 + g * 8];
            floatx4 s = floatx4{0.f, 0.f, 0.f, 0.f};
            s = mfma_bf16(kr0, qreg[0], s);
            s = mfma_bf16(kr1, qreg[1], s);
            sf[kf] = s;
        }
        __builtin_amdgcn_s_setprio(0);

        const bool diag = (kv0 + 63 > q0 + wq);   // wave-uniform
        const int qg = q0 + wq + l15;
        float tmax = -__builtin_inff();
        if (diag) {
            #pragma unroll
            for (int kf = 0; kf < 4; kf++) {
                #pragma unroll
                for (int r = 0; r < 4; r++) {
                    int key = kv0 + kf * 16 + g * 4 + r;
                    float x = sf[kf][r];
                    if (key > qg) x = -1e9f;
                    sf[kf][r] = x;
                    tmax = fmaxf(tmax, x);
                }
            }
        } else {
            #pragma unroll
            for (int kf = 0; kf < 4; kf++)
                #pragma unroll
                for (int r = 0; r < 4; r++)
                    tmax = fmaxf(tmax, sf[kf][r]);
        }
        // per-lane defer-max: no cross-lane traffic in the common case
        if (!__all(tmax <= m + 8.0f)) {
            tmax = fmaxf(tmax, __shfl_xor(tmax, 16, 64));
            tmax = fmaxf(tmax, __shfl_xor(tmax, 32, 64));
            float mn = fmaxf(m, tmax);
            float f  = fexp2(m - mn);
            m = mn;
            lsum *= f;
            #pragma unroll
            for (int r = 0; r < 4; r++) {
                float fr = __shfl(f, g * 4 + r, 64);
                #pragma unroll
                for (int df = 0; df < 4; df++)
                    of[df][r] *= fr;
            }
        }
        float rs = 0.f;
        #pragma unroll
        for (int kf = 0; kf < 4; kf++) {
            #pragma unroll
            for (int r = 0; r < 4; r++) {
                float p = fexp2(sf[kf][r] - m);
                sf[kf][r] = p;
                rs += p;
            }
        }
        lsum += rs;
        // pack P into lane-local A-frags via v_cvt_pk_bf16_f32
        short8 pa[2];
        #pragma unroll
        for (int ks = 0; ks < 2; ks++) {
            union { short8 s; uint u[4]; } pu;
            #pragma unroll
            for (int w = 0; w < 4; w++) {
                const int kf = 2 * ks + (w >> 1);
                float lo = sf[kf][(w & 1) * 2 + 0];
                float hi = sf[kf][(w & 1) * 2 + 1];
                asm("v_cvt_pk_bf16_f32 %0, %1, %2"
                    : "=v"(pu.u[w]) : "v"(lo), "v"(hi));
            }
            pa[ks] = pu.s;
        }
        // PV
        __builtin_amdgcn_s_setprio(1);
        #pragma unroll
        for (int df = 0; df < 4; df++) {
            #pragma unroll
            for (int ks = 0; ks < 2; ks++) {
                const int vb = (df * 16 + l15) * 72 + ks * 32 + g * 4;
                uint2 v0 = *(const uint2*)&Vc[vb];
                uint2 v1 = *(const uint2*)&Vc[vb + 16];
                union { short8 s; uint4 u; } vv;
                vv.u.x = v0.x; vv.u.y = v0.y; vv.u.z = v1.x; vv.u.w = v1.y;
                of[df] = mfma_bf16(pa[ks], vv.s, of[df]);
            }
        }
        __builtin_amdgcn_s_setprio(0);
    };

    short8 kA, vA, kB, vB;
    load_tile(0, kA, vA);
    if (nt > 1) load_tile(1, kB, vB);
    write_tile(0, kA, vA);
    __syncthreads();

    for (int t = 0; t < nt; t += 2) {
        if (t + 2 < nt) load_tile(t + 2, kA, vA);
        compute_tile(t, Kl[0], Vt[0]);
        write_tile(1, kB, vB);
        __syncthreads();
        if (t + 3 < nt) load_tile(t + 3, kB, vB);
        compute_tile(t + 1, Kl[1], Vt[1]);
        if (t + 2 < nt) write_tile(0, kA, vA);
        __syncthreads();
    }

    // epilogue: reduce l across g-lanes once, O /= l, store attn (b,s,H) bf16
    lsum += __shfl_xor(lsum, 16, 64);
    lsum += __shfl_xor(lsum, 32, 64);
    #pragma unroll
    for (int r = 0; r < 4; r++) {
        float lr = __shfl(lsum, g * 4 + r, 64);
        float inv = 1.0f / lr;
        int q = q0 + wq + g * 4 + r;
        #pragma unroll
        for (int df = 0; df < 4; df++)
            attn[((size_t)bb * SEQ + q) * HID + hh * 64 + df * 16 + l15] =
                f2bf(of[df][r] * inv);
    }
}

// ---------------------------------------------------------------------------
// Kernel 3: out = attn @ w_out (M=4096, N=1024, K=1024), 2-phase pipelined
// double-buffer (round-9 form), fp32 output.
// ---------------------------------------------------------------------------
__global__ __launch_bounds__(256) void out_proj_kernel(
    const ushort* __restrict__ attn,    // (4096,1024) bf16
    const ushort* __restrict__ woutT,   // (1024,1024) bf16 (N,K)
    float* __restrict__ out)
{
    __shared__ ushort Al[2][128 * 32];
    __shared__ ushort Bl[2][128 * 32];
    const int tid  = threadIdx.x;
    const int lane = tid & 63;
    const int wv   = tid >> 6;
    const int g    = lane >> 4;
    const int l15  = lane & 15;

    const int lin  = blockIdx.x + 8 * blockIdx.y;   // 0..255
    const int xcd  = lin & 7;
    const int slot = lin >> 3;                      // 0..31
    const int cxi  = xcd & 1, cyi = xcd >> 1;
    const int sx   = slot & 3, sy = slot >> 2;      // 4x8
    const int n0   = (cxi * 4 + sx) * 128;
    const int m0   = (cyi * 8 + sy) * 128;

    const int wr = (wv >> 1) * 64;
    const int wc = (wv & 1) * 64;
    const int rowl = lane >> 2;
    const int kcol = (lane & 3) * 8;

    floatx4 acc[4][4];
    #pragma unroll
    for (int a = 0; a < 4; a++)
        #pragma unroll
        for (int bq = 0; bq < 4; bq++)
            acc[a][bq] = floatx4{0.f, 0.f, 0.f, 0.f};

    const ushort* ga = attn  + (size_t)(m0 + wv * 32 + rowl) * 1024 + kcol;
    const ushort* gb = woutT + (size_t)(n0 + wv * 32 + rowl) * 1024 + kcol;
    const int lofs = wv * 1024;

    gload16(ga,             &Al[0][lofs]);
    gload16(ga + 16 * 1024, &Al[0][lofs + 512]);
    gload16(gb,             &Bl[0][lofs]);
    gload16(gb + 16 * 1024, &Bl[0][lofs + 512]);
    asm volatile("s_waitcnt vmcnt(0)" ::: "memory");
    __builtin_amdgcn_s_barrier();

    for (int it = 0; it < 32; it++) {
        const int cur = it & 1;
        if (it + 1 < 32) {
            const int k0 = (it + 1) * 32;
            const int nxt = cur ^ 1;
            gload16(ga + k0,             &Al[nxt][lofs]);
            gload16(ga + k0 + 16 * 1024, &Al[nxt][lofs + 512]);
            gload16(gb + k0,             &Bl[nxt][lofs]);
            gload16(gb + k0 + 16 * 1024, &Bl[nxt][lofs + 512]);
        }
        short8 af[4], bfr[4];
        #pragma unroll
        for (int fm = 0; fm < 4; fm++)
            af[fm] = *(const short8*)&Al[cur][(wr + fm * 16 + l15) * 32 + g * 8];
        #pragma unroll
        for (int fn = 0; fn < 4; fn++)
            bfr[fn] = *(const short8*)&Bl[cur][(wc + fn * 16 + l15) * 32 + g * 8];
        #pragma unroll
        for (int fm = 0; fm < 4; fm++)
            #pragma unroll
            for (int fn = 0; fn < 4; fn++)
                acc[fm][fn] = mfma_bf16(af[fm], bfr[fn], acc[fm][fn]);
        asm volatile("s_waitcnt vmcnt(0)" ::: "memory");
        __builtin_amdgcn_s_barrier();
    }
    #pragma unroll
    for (int fm = 0; fm < 4; fm++)
        #pragma unroll
        for (int fn = 0; fn < 4; fn++)
            #pragma unroll
            for (int r = 0; r < 4; r++) {
                int row = m0 + wr + fm * 16 + g * 4 + r;
                int col = n0 + wc + fn * 16 + l15;
                out[(size_t)row * 1024 + col] = acc[fm][fn][r];
            }
}

// ---------------------------------------------------------------------------
extern "C" void kernel_launch(void* const* d_in, const int* in_sizes, int n_in,
                              void* d_out, int out_size, void* d_ws, size_t ws_size,
                              hipStream_t stream)
{
    const float* hidden = (const float*)d_in[0];
    const float* wqkv   = (const float*)d_in[1];
    const float* wout   = (const float*)d_in[2];
    float* out = (float*)d_out;

    const size_t NELEM = (size_t)2 * SEQ * HID;   // 4,194,304
    ushort* Qb    = (ushort*)d_ws;
    ushort* Kb    = Qb + NELEM;
    ushort* Vb    = Kb + NELEM;
    ushort* hbf   = Vb + NELEM;                   // hidden bf16; later reused as attn
    ushort* wqkvT = hbf + NELEM;                  // 3072*1024
    ushort* woutT = wqkvT + (size_t)3072 * 1024;  // 1024*1024
    ushort* attnb = hbf;                          // alias: lifetime disjoint

    convert_bf16_kernel<<<2048, 256, 0, stream>>>(hidden, hbf, (int)NELEM);
    transpose_bf16_kernel<<<dim3(48, 16), 256, 0, stream>>>(wqkv, wqkvT, 1024, 3072);
    transpose_bf16_kernel<<<dim3(16, 16), 256, 0, stream>>>(wout, woutT, 1024, 1024);
    qkv_rope_kernel<<<dim3(12, 16), 1024, 0, stream>>>(hbf, wqkvT, Qb, Kb, Vb);
    attn_kernel<<<dim3(16, NHEADS, 2), 512, 0, stream>>>(Qb, Kb, Vb, attnb);
    out_proj_kernel<<<dim3(8, 32), 256, 0, stream>>>(attnb, woutT, out);
}

// Round 15
// 127.907 us; speedup vs baseline: 1.1293x; 1.0426x over previous
//
#include <hip/hip_runtime.h>

#define SEQ   2048
#define NHEADS 16
#define HDIM  64
#define HID   1024
#define ROT   32

typedef __attribute__((ext_vector_type(8))) short  short8;
typedef __attribute__((ext_vector_type(4))) float  floatx4;

__device__ __forceinline__ ushort f2bf(float f) {
    union { float f; uint u; } v; v.f = f;
    uint x = v.u;
    uint r = (x + 0x7FFFu + ((x >> 16) & 1u)) >> 16;
    return (ushort)r;
}

__device__ __forceinline__ float fexp2(float x) {
    return __builtin_amdgcn_exp2f(x);     // v_exp_f32 directly
}

__device__ __forceinline__ floatx4 mfma_bf16(short8 a, short8 b, floatx4 c) {
    return __builtin_amdgcn_mfma_f32_16x16x32_bf16(a, b, c, 0, 0, 0);
}

__device__ __forceinline__ void gload16(const ushort* g, ushort* l) {
    __builtin_amdgcn_global_load_lds(
        (const __attribute__((address_space(1))) void*)g,
        (__attribute__((address_space(3))) void*)l, 16, 0, 0);
}

// ---------------------------------------------------------------------------
// Pre-pass A: fp32 -> bf16 elementwise (hidden)
// ---------------------------------------------------------------------------
__global__ __launch_bounds__(256) void convert_bf16_kernel(
    const float* __restrict__ src, ushort* __restrict__ dst, int n)
{
    int i = (blockIdx.x * 256 + threadIdx.x) * 8;
    if (i >= n) return;
    float4 a = *(const float4*)(src + i);
    float4 b = *(const float4*)(src + i + 4);
    short8 v;
    v[0] = (short)f2bf(a.x); v[1] = (short)f2bf(a.y);
    v[2] = (short)f2bf(a.z); v[3] = (short)f2bf(a.w);
    v[4] = (short)f2bf(b.x); v[5] = (short)f2bf(b.y);
    v[6] = (short)f2bf(b.z); v[7] = (short)f2bf(b.w);
    *(short8*)(dst + i) = v;
}

// ---------------------------------------------------------------------------
// Pre-pass B: fp32 (K,N) -> bf16 (N,K) transpose-convert. Tile 64x64.
// ---------------------------------------------------------------------------
__global__ __launch_bounds__(256) void transpose_bf16_kernel(
    const float* __restrict__ src, ushort* __restrict__ dst, int K, int N)
{
    __shared__ ushort Tl[64 * 68];
    const int k0 = blockIdx.y * 64, n0 = blockIdx.x * 64;
    const int tid = threadIdx.x;
    #pragma unroll
    for (int i = 0; i < 4; i++) {
        int lin = tid + 256 * i;
        int row = lin >> 4;
        int c4  = (lin & 15) * 4;
        float4 v = *(const float4*)(src + (size_t)(k0 + row) * N + n0 + c4);
        uint2 u;
        u.x = (uint)f2bf(v.x) | ((uint)f2bf(v.y) << 16);
        u.y = (uint)f2bf(v.z) | ((uint)f2bf(v.w) << 16);
        *(uint2*)&Tl[row * 68 + c4] = u;
    }
    __syncthreads();
    #pragma unroll
    for (int j = 0; j < 2; j++) {
        int lin = tid + 256 * j;
        int n = lin >> 3, c = lin & 7;
        short8 v;
        #pragma unroll
        for (int u = 0; u < 8; u++) v[u] = (short)Tl[(c * 8 + u) * 68 + n];
        *(short8*)(dst + (size_t)(n0 + n) * K + k0 + c * 8) = v;
    }
}

// ---------------------------------------------------------------------------
// Kernel 1: qkv = hidden @ w_qkv (M=4096, N=3072, K=1024) bf16 inputs.
// 128(M) x 256(N) tile, 8 waves, r12 2-phase pipelined double-buffer +
// T2 LDS swizzle (both-sides): LDS stays linear (global_load_lds rule),
// the bank permutation is applied on the global SOURCE chunk
// (c_src = (t&3) ^ ((row>>1)&3)) and on the ds_read address
// (idx ^= ((row>>1)&3)<<3). 64B rows were 8-way conflicted -> 2-way (free).
// Fused RoPE + head split. Q pre-scaled by 0.125*log2(e).
// Q,K (b,h,s,d); V (b,h,d,s).
// ---------------------------------------------------------------------------
__global__ __launch_bounds__(512) void qkv_rope_kernel(
    const ushort* __restrict__ hbf,     // (4096,1024) bf16
    const ushort* __restrict__ wqkvT,   // (3072,1024) bf16 (N,K)
    ushort* __restrict__ Qb, ushort* __restrict__ Kb, ushort* __restrict__ Vb)
{
    __shared__ ushort Al[2][4096];      // A tile 128x32
    __shared__ ushort Bl[2][8192];      // B tile 256x32
    const int tid  = threadIdx.x;
    const int lane = tid & 63;
    const int wv   = tid >> 6;          // 0..7
    const int g    = lane >> 4;
    const int l15  = lane & 15;

    // XCD-chunked remap over the 12(n) x 32(m) tile grid: each XCD owns a
    // 6(n) x 8(m) chunk (A 2MB + B 3MB ~ L2-resident).
    const int lin  = blockIdx.x + 12 * blockIdx.y;  // 0..383
    const int xcd  = lin & 7;
    const int slot = lin >> 3;                      // 0..47
    const int cxi  = xcd & 1, cyi = xcd >> 1;       // 2(n) x 4(m) chunks
    const int sx   = slot % 6, sy = slot / 6;       // 6 x 8
    const int n0   = (cxi * 6 + sx) * 256;
    const int m0   = (cyi * 8 + sy) * 128;

    const int wr = (wv >> 2) * 64;      // 0,64      (2 m-waves)
    const int wc = (wv & 3) * 64;       // 0..192    (4 n-waves)

    floatx4 acc[4][4];
    #pragma unroll
    for (int a = 0; a < 4; a++)
        #pragma unroll
        for (int bq = 0; bq < 4; bq++)
            acc[a][bq] = floatx4{0.f, 0.f, 0.f, 0.f};

    // pre-swizzled source chunk: c_src = (t&3) ^ ((row>>1)&3), row = t>>2
    const int gsw = ((tid & 3) ^ ((tid >> 3) & 3)) * 8;
    const ushort* ga  = hbf   + (size_t)(m0 + (tid >> 2)) * 1024 + gsw;
    const ushort* gb0 = wqkvT + (size_t)(n0 + (tid >> 2)) * 1024 + gsw;
    const ushort* gb1 = gb0 + (size_t)128 * 1024;   // rows +128: same XOR field
    const int wofs = wv * 512;          // wave-uniform LDS base (ushorts)

    auto stage = [&](int t, int buf) {
        const int k0 = t * 32;
        gload16(ga  + k0, &Al[buf][wofs]);
        gload16(gb0 + k0, &Bl[buf][wofs]);
        gload16(gb1 + k0, &Bl[buf][4096 + wofs]);
    };

    stage(0, 0);
    asm volatile("s_waitcnt vmcnt(0)" ::: "memory");
    __builtin_amdgcn_s_barrier();

    for (int it = 0; it < 32; it++) {
        const int cur = it & 1;
        if (it + 1 < 32) stage(it + 1, cur ^ 1);
        short8 af[4], bfr[4];
        #pragma unroll
        for (int fm = 0; fm < 4; fm++) {
            const int ra = wr + fm * 16 + l15;
            af[fm] = *(const short8*)&Al[cur][(ra * 32 + g * 8) ^ (((ra >> 1) & 3) << 3)];
        }
        #pragma unroll
        for (int fn = 0; fn < 4; fn++) {
            const int rb = wc + fn * 16 + l15;
            bfr[fn] = *(const short8*)&Bl[cur][(rb * 32 + g * 8) ^ (((rb >> 1) & 3) << 3)];
        }
        #pragma unroll
        for (int fm = 0; fm < 4; fm++)
            #pragma unroll
            for (int fn = 0; fn < 4; fn++)
                acc[fm][fn] = mfma_bf16(af[fm], bfr[fn], acc[fm][fn]);
        asm volatile("s_waitcnt vmcnt(0)" ::: "memory");
        __builtin_amdgcn_s_barrier();
    }

    // epilogue: per-wave output rows m0+wr+fm*16+g*4+r, cols n0+wc+fn*16+l15
    #pragma unroll
    for (int fn = 0; fn < 4; fn++) {
        const int c    = n0 + wc + fn * 16 + l15;
        const int mp   = c / 384;
        const int rem  = c - mp * 384;
        const int tsel = rem >> 7;                    // 0=q 1=k 2=v
        const int j    = (rem >> 6) & 1;
        const int d    = rem & 63;
        const int head = mp * 2 + j;
        ushort* basep = (tsel == 0) ? Qb : (tsel == 1) ? Kb : Vb;
        const bool rope = (tsel < 2) && (d < ROT);
        // Q carries 1/sqrt(64) * log2(e) so attention uses exp2 directly
        const float qscale = (tsel == 0) ? 0.18033688011112042f : 1.0f;
        float freq = 0.f;
        if (rope) {
            freq = exp2f((float)(d >> 1) * -0.830482023721841f);
        }
        #pragma unroll
        for (int fm = 0; fm < 4; fm++) {
            #pragma unroll
            for (int r = 0; r < 4; r++) {
                int row = m0 + wr + fm * 16 + g * 4 + r;
                int bb  = row >> 11;
                int s   = row & 2047;
                float val = acc[fm][fn][r];
                float pv  = __shfl_xor(val, 1, 64);
                float outv = val;
                if (rope) {
                    float ang = (float)s * freq;
                    float sn, cs;
                    __sincosf(ang, &sn, &cs);
                    outv = ((d & 1) == 0) ? (val * cs - pv * sn)
                                          : (val * cs + pv * sn);
                }
                outv *= qscale;
                size_t off;
                if (tsel == 2)
                    off = ((size_t)(bb * NHEADS + head) * HDIM + d) * SEQ + s;
                else
                    off = ((size_t)(bb * NHEADS + head) * SEQ + s) * HDIM + d;
                basep[off] = f2bf(outv);
            }
        }
    }
}

// ---------------------------------------------------------------------------
// Kernel 2: flash attention, causal. 512 threads = 8 waves x 16 q-rows
// (Q tile 128), KV tiles 64. Complementary-qb pairing; 2-deep register
// prefetch + LDS double-buffer; exp2-domain softmax with per-lane defer-max
// (cross-lane reduces only on rescale) and epilogue-deferred l-sum.
// ---------------------------------------------------------------------------
__global__ __launch_bounds__(512, 4) void attn_kernel(
    const ushort* __restrict__ Qb, const ushort* __restrict__ Kb,
    const ushort* __restrict__ Vb, ushort* __restrict__ attn)
{
    __shared__ ushort Kl[2][64 * 72];      // [key][d], stride 72
    __shared__ ushort Vt[2][64 * 72];      // [d][key], stride 72

    const int tid  = threadIdx.x;
    const int lane = tid & 63;
    const int wv   = tid >> 6;             // 0..7
    const int g    = lane >> 4;
    const int l15  = lane & 15;

    const int l    = blockIdx.x + 16 * blockIdx.y + 256 * blockIdx.z;
    const int half = l >> 8;
    const int xx   = l & 15;
    const int hh   = (l >> 4) & 15;
    const int qb   = half ? xx : 15 - xx;
    const int bb   = half;

    const int q0 = qb * 128;
    const int wq = wv * 16;
    const size_t kvbase = (size_t)(bb * NHEADS + hh) * SEQ * HDIM;

    const int srow = tid >> 3;             // 0..63 staging row
    const int sch  = (tid & 7) * 8;        // staging col (ushort)

    short8 qreg[2];
    #pragma unroll
    for (int ks = 0; ks < 2; ks++)
        qreg[ks] = *(const short8*)(Qb + kvbase +
            (size_t)(q0 + wq + l15) * HDIM + ks * 32 + g * 8);

    float m = -__builtin_inff();
    float lsum = 0.f;                      // per-lane partial (16 keys/row)
    floatx4 of[4];
    #pragma unroll
    for (int df = 0; df < 4; df++) of[df] = floatx4{0.f, 0.f, 0.f, 0.f};

    const int nt = 2 * qb + 2;             // always even

    auto load_tile = [&](int tt, short8& kr, short8& vr) {
        const int kv = tt * 64;
        kr = *(const short8*)(Kb + kvbase + (size_t)(kv + srow) * HDIM + sch);
        vr = *(const short8*)(Vb + kvbase + (size_t)srow * SEQ + kv + sch);
    };
    auto write_tile = [&](int buf, short8& kr, short8& vr) {
        *(short8*)&Kl[buf][srow * 72 + sch] = kr;
        *(short8*)&Vt[buf][srow * 72 + sch] = vr;
    };
    auto compute_tile = [&](int t, const ushort* Kc, const ushort* Vc) {
        const int kv0 = t * 64;
        if (kv0 > q0 + wq + 15) return;    // fully-masked for this wave
        // QK^T (swapped): sf[kf], lane l15 = q-row, key = kv0 + kf*16 + g*4 + r
        floatx4 sf[4];
        __builtin_amdgcn_s_setprio(1);
        #pragma unroll
        for (int kf = 0; kf < 4; kf++) {
            short8 kr0 = *(const short8*)&Kc[(kf * 16 + l15) * 72 + g * 8];
            short8 kr1 = *(const short8*)&Kc[(kf * 16 + l15) * 72 + 32 + g * 8];
            floatx4 s = floatx4{0.f, 0.f, 0.f, 0.f};
            s = mfma_bf16(kr0, qreg[0], s);
            s = mfma_bf16(kr1, qreg[1], s);
            sf[kf] = s;
        }
        __builtin_amdgcn_s_setprio(0);

        const bool diag = (kv0 + 63 > q0 + wq);   // wave-uniform
        const int qg = q0 + wq + l15;
        float tmax = -__builtin_inff();
        if (diag) {
            #pragma unroll
            for (int kf = 0; kf < 4; kf++) {
                #pragma unroll
                for (int r = 0; r < 4; r++) {
                    int key = kv0 + kf * 16 + g * 4 + r;
                    float x = sf[kf][r];
                    if (key > qg) x = -1e9f;
                    sf[kf][r] = x;
                    tmax = fmaxf(tmax, x);
                }
            }
        } else {
            #pragma unroll
            for (int kf = 0; kf < 4; kf++)
                #pragma unroll
                for (int r = 0; r < 4; r++)
                    tmax = fmaxf(tmax, sf[kf][r]);
        }
        // per-lane defer-max: no cross-lane traffic in the common case
        if (!__all(tmax <= m + 8.0f)) {
            tmax = fmaxf(tmax, __shfl_xor(tmax, 16, 64));
            tmax = fmaxf(tmax, __shfl_xor(tmax, 32, 64));
            float mn = fmaxf(m, tmax);
            float f  = fexp2(m - mn);
            m = mn;
            lsum *= f;
            #pragma unroll
            for (int r = 0; r < 4; r++) {
                float fr = __shfl(f, g * 4 + r, 64);
                #pragma unroll
                for (int df = 0; df < 4; df++)
                    of[df][r] *= fr;
            }
        }
        float rs = 0.f;
        #pragma unroll
        for (int kf = 0; kf < 4; kf++) {
            #pragma unroll
            for (int r = 0; r < 4; r++) {
                float p = fexp2(sf[kf][r] - m);
                sf[kf][r] = p;
                rs += p;
            }
        }
        lsum += rs;
        // pack P into lane-local A-frags via v_cvt_pk_bf16_f32
        short8 pa[2];
        #pragma unroll
        for (int ks = 0; ks < 2; ks++) {
            union { short8 s; uint u[4]; } pu;
            #pragma unroll
            for (int w = 0; w < 4; w++) {
                const int kf = 2 * ks + (w >> 1);
                float lo = sf[kf][(w & 1) * 2 + 0];
                float hi = sf[kf][(w & 1) * 2 + 1];
                asm("v_cvt_pk_bf16_f32 %0, %1, %2"
                    : "=v"(pu.u[w]) : "v"(lo), "v"(hi));
            }
            pa[ks] = pu.s;
        }
        // PV
        __builtin_amdgcn_s_setprio(1);
        #pragma unroll
        for (int df = 0; df < 4; df++) {
            #pragma unroll
            for (int ks = 0; ks < 2; ks++) {
                const int vb = (df * 16 + l15) * 72 + ks * 32 + g * 4;
                uint2 v0 = *(const uint2*)&Vc[vb];
                uint2 v1 = *(const uint2*)&Vc[vb + 16];
                union { short8 s; uint4 u; } vv;
                vv.u.x = v0.x; vv.u.y = v0.y; vv.u.z = v1.x; vv.u.w = v1.y;
                of[df] = mfma_bf16(pa[ks], vv.s, of[df]);
            }
        }
        __builtin_amdgcn_s_setprio(0);
    };

    short8 kA, vA, kB, vB;
    load_tile(0, kA, vA);
    if (nt > 1) load_tile(1, kB, vB);
    write_tile(0, kA, vA);
    __syncthreads();

    for (int t = 0; t < nt; t += 2) {
        if (t + 2 < nt) load_tile(t + 2, kA, vA);
        compute_tile(t, Kl[0], Vt[0]);
        write_tile(1, kB, vB);
        __syncthreads();
        if (t + 3 < nt) load_tile(t + 3, kB, vB);
        compute_tile(t + 1, Kl[1], Vt[1]);
        if (t + 2 < nt) write_tile(0, kA, vA);
        __syncthreads();
    }

    // epilogue: reduce l across g-lanes once, O /= l, store attn (b,s,H) bf16
    lsum += __shfl_xor(lsum, 16, 64);
    lsum += __shfl_xor(lsum, 32, 64);
    #pragma unroll
    for (int r = 0; r < 4; r++) {
        float lr = __shfl(lsum, g * 4 + r, 64);
        float inv = 1.0f / lr;
        int q = q0 + wq + g * 4 + r;
        #pragma unroll
        for (int df = 0; df < 4; df++)
            attn[((size_t)bb * SEQ + q) * HID + hh * 64 + df * 16 + l15] =
                f2bf(of[df][r] * inv);
    }
}

// ---------------------------------------------------------------------------
// Kernel 3: out = attn @ w_out (M=4096, N=1024, K=1024), 2-phase pipelined
// double-buffer + T2 both-sides swizzle (same scheme as kernel 1).
// ---------------------------------------------------------------------------
__global__ __launch_bounds__(256) void out_proj_kernel(
    const ushort* __restrict__ attn,    // (4096,1024) bf16
    const ushort* __restrict__ woutT,   // (1024,1024) bf16 (N,K)
    float* __restrict__ out)
{
    __shared__ ushort Al[2][128 * 32];
    __shared__ ushort Bl[2][128 * 32];
    const int tid  = threadIdx.x;
    const int lane = tid & 63;
    const int wv   = tid >> 6;
    const int g    = lane >> 4;
    const int l15  = lane & 15;

    const int lin  = blockIdx.x + 8 * blockIdx.y;   // 0..255
    const int xcd  = lin & 7;
    const int slot = lin >> 3;                      // 0..31
    const int cxi  = xcd & 1, cyi = xcd >> 1;
    const int sx   = slot & 3, sy = slot >> 2;      // 4x8
    const int n0   = (cxi * 4 + sx) * 128;
    const int m0   = (cyi * 8 + sy) * 128;

    const int wr = (wv >> 1) * 64;
    const int wc = (wv & 1) * 64;
    const int rowl = lane >> 2;
    // pre-swizzled source chunk: rows wv*32+rowl and +16 share the XOR field
    const int kcol = ((lane & 3) ^ ((lane >> 3) & 3)) * 8;

    floatx4 acc[4][4];
    #pragma unroll
    for (int a = 0; a < 4; a++)
        #pragma unroll
        for (int bq = 0; bq < 4; bq++)
            acc[a][bq] = floatx4{0.f, 0.f, 0.f, 0.f};

    const ushort* ga = attn  + (size_t)(m0 + wv * 32 + rowl) * 1024 + kcol;
    const ushort* gb = woutT + (size_t)(n0 + wv * 32 + rowl) * 1024 + kcol;
    const int lofs = wv * 1024;

    gload16(ga,             &Al[0][lofs]);
    gload16(ga + 16 * 1024, &Al[0][lofs + 512]);
    gload16(gb,             &Bl[0][lofs]);
    gload16(gb + 16 * 1024, &Bl[0][lofs + 512]);
    asm volatile("s_waitcnt vmcnt(0)" ::: "memory");
    __builtin_amdgcn_s_barrier();

    for (int it = 0; it < 32; it++) {
        const int cur = it & 1;
        if (it + 1 < 32) {
            const int k0 = (it + 1) * 32;
            const int nxt = cur ^ 1;
            gload16(ga + k0,             &Al[nxt][lofs]);
            gload16(ga + k0 + 16 * 1024, &Al[nxt][lofs + 512]);
            gload16(gb + k0,             &Bl[nxt][lofs]);
            gload16(gb + k0 + 16 * 1024, &Bl[nxt][lofs + 512]);
        }
        short8 af[4], bfr[4];
        #pragma unroll
        for (int fm = 0; fm < 4; fm++) {
            const int ra = wr + fm * 16 + l15;
            af[fm] = *(const short8*)&Al[cur][(ra * 32 + g * 8) ^ (((ra >> 1) & 3) << 3)];
        }
        #pragma unroll
        for (int fn = 0; fn < 4; fn++) {
            const int rb = wc + fn * 16 + l15;
            bfr[fn] = *(const short8*)&Bl[cur][(rb * 32 + g * 8) ^ (((rb >> 1) & 3) << 3)];
        }
        #pragma unroll
        for (int fm = 0; fm < 4; fm++)
            #pragma unroll
            for (int fn = 0; fn < 4; fn++)
                acc[fm][fn] = mfma_bf16(af[fm], bfr[fn], acc[fm][fn]);
        asm volatile("s_waitcnt vmcnt(0)" ::: "memory");
        __builtin_amdgcn_s_barrier();
    }
    #pragma unroll
    for (int fm = 0; fm < 4; fm++)
        #pragma unroll
        for (int fn = 0; fn < 4; fn++)
            #pragma unroll
            for (int r = 0; r < 4; r++) {
                int row = m0 + wr + fm * 16 + g * 4 + r;
                int col = n0 + wc + fn * 16 + l15;
                out[(size_t)row * 1024 + col] = acc[fm][fn][r];
            }
}

// ---------------------------------------------------------------------------
extern "C" void kernel_launch(void* const* d_in, const int* in_sizes, int n_in,
                              void* d_out, int out_size, void* d_ws, size_t ws_size,
                              hipStream_t stream)
{
    const float* hidden = (const float*)d_in[0];
    const float* wqkv   = (const float*)d_in[1];
    const float* wout   = (const float*)d_in[2];
    float* out = (float*)d_out;

    const size_t NELEM = (size_t)2 * SEQ * HID;   // 4,194,304
    ushort* Qb    = (ushort*)d_ws;
    ushort* Kb    = Qb + NELEM;
    ushort* Vb    = Kb + NELEM;
    ushort* hbf   = Vb + NELEM;                   // hidden bf16; later reused as attn
    ushort* wqkvT = hbf + NELEM;                  // 3072*1024
    ushort* woutT = wqkvT + (size_t)3072 * 1024;  // 1024*1024
    ushort* attnb = hbf;                          // alias: lifetime disjoint

    convert_bf16_kernel<<<2048, 256, 0, stream>>>(hidden, hbf, (int)NELEM);
    transpose_bf16_kernel<<<dim3(48, 16), 256, 0, stream>>>(wqkv, wqkvT, 1024, 3072);
    transpose_bf16_kernel<<<dim3(16, 16), 256, 0, stream>>>(wout, woutT, 1024, 1024);
    qkv_rope_kernel<<<dim3(12, 32), 512, 0, stream>>>(hbf, wqkvT, Qb, Kb, Vb);
    attn_kernel<<<dim3(16, NHEADS, 2), 512, 0, stream>>>(Qb, Kb, Vb, attnb);
    out_proj_kernel<<<dim3(8, 32), 256, 0, stream>>>(attnb, woutT, out);
}

// Round 16
// 126.721 us; speedup vs baseline: 1.1398x; 1.0094x over previous
//
#include <hip/hip_runtime.h>

#define SEQ   2048
#define NHEADS 16
#define HDIM  64
#define HID   1024
#define ROT   32

typedef __attribute__((ext_vector_type(8))) short  short8;
typedef __attribute__((ext_vector_type(4))) float  floatx4;

__device__ __forceinline__ ushort f2bf(float f) {
    union { float f; uint u; } v; v.f = f;
    uint x = v.u;
    uint r = (x + 0x7FFFu + ((x >> 16) & 1u)) >> 16;
    return (ushort)r;
}

__device__ __forceinline__ float fexp2(float x) {
    return __builtin_amdgcn_exp2f(x);     // v_exp_f32 directly
}

__device__ __forceinline__ floatx4 mfma_bf16(short8 a, short8 b, floatx4 c) {
    return __builtin_amdgcn_mfma_f32_16x16x32_bf16(a, b, c, 0, 0, 0);
}

__device__ __forceinline__ void gload16(const ushort* g, ushort* l) {
    __builtin_amdgcn_global_load_lds(
        (const __attribute__((address_space(1))) void*)g,
        (__attribute__((address_space(3))) void*)l, 16, 0, 0);
}

// ---------------------------------------------------------------------------
// Pre-pass A: fp32 -> bf16 elementwise (hidden)
// ---------------------------------------------------------------------------
__global__ __launch_bounds__(256) void convert_bf16_kernel(
    const float* __restrict__ src, ushort* __restrict__ dst, int n)
{
    int i = (blockIdx.x * 256 + threadIdx.x) * 8;
    if (i >= n) return;
    float4 a = *(const float4*)(src + i);
    float4 b = *(const float4*)(src + i + 4);
    short8 v;
    v[0] = (short)f2bf(a.x); v[1] = (short)f2bf(a.y);
    v[2] = (short)f2bf(a.z); v[3] = (short)f2bf(a.w);
    v[4] = (short)f2bf(b.x); v[5] = (short)f2bf(b.y);
    v[6] = (short)f2bf(b.z); v[7] = (short)f2bf(b.w);
    *(short8*)(dst + i) = v;
}

// ---------------------------------------------------------------------------
// Pre-pass B: fp32 (K,N) -> bf16 (N,K) transpose-convert. Tile 64x64.
// ---------------------------------------------------------------------------
__global__ __launch_bounds__(256) void transpose_bf16_kernel(
    const float* __restrict__ src, ushort* __restrict__ dst, int K, int N)
{
    __shared__ ushort Tl[64 * 68];
    const int k0 = blockIdx.y * 64, n0 = blockIdx.x * 64;
    const int tid = threadIdx.x;
    #pragma unroll
    for (int i = 0; i < 4; i++) {
        int lin = tid + 256 * i;
        int row = lin >> 4;
        int c4  = (lin & 15) * 4;
        float4 v = *(const float4*)(src + (size_t)(k0 + row) * N + n0 + c4);
        uint2 u;
        u.x = (uint)f2bf(v.x) | ((uint)f2bf(v.y) << 16);
        u.y = (uint)f2bf(v.z) | ((uint)f2bf(v.w) << 16);
        *(uint2*)&Tl[row * 68 + c4] = u;
    }
    __syncthreads();
    #pragma unroll
    for (int j = 0; j < 2; j++) {
        int lin = tid + 256 * j;
        int n = lin >> 3, c = lin & 7;
        short8 v;
        #pragma unroll
        for (int u = 0; u < 8; u++) v[u] = (short)Tl[(c * 8 + u) * 68 + n];
        *(short8*)(dst + (size_t)(n0 + n) * K + k0 + c * 8) = v;
    }
}

// ---------------------------------------------------------------------------
// Kernel 1: qkv = hidden @ w_qkv (M=4096, N=3072, K=1024) bf16 inputs.
// 128(M) x 256(N) tile, 8 waves, T4 depth-2 counted-vmcnt pipeline:
// 3 LDS buffers (72KB; grid 1.5 blocks/CU so residency unchanged vs 2-buf),
// steady-state s_waitcnt vmcnt(3) — next tile completes, tile+2 stays in
// flight across the barrier (never drain-0 mid-loop). T2 both-sides swizzle
// (conflicts measured 0). Fused RoPE + head split. Q pre-scaled by
// 0.125*log2(e). Q,K (b,h,s,d); V (b,h,d,s).
// ---------------------------------------------------------------------------
__global__ __launch_bounds__(512) void qkv_rope_kernel(
    const ushort* __restrict__ hbf,     // (4096,1024) bf16
    const ushort* __restrict__ wqkvT,   // (3072,1024) bf16 (N,K)
    ushort* __restrict__ Qb, ushort* __restrict__ Kb, ushort* __restrict__ Vb)
{
    __shared__ ushort Al[3 * 4096];     // A tile 128x32 per buffer
    __shared__ ushort Bl[3 * 8192];     // B tile 256x32 per buffer
    const int tid  = threadIdx.x;
    const int lane = tid & 63;
    const int wv   = tid >> 6;          // 0..7
    const int g    = lane >> 4;
    const int l15  = lane & 15;

    // XCD-chunked remap over the 12(n) x 32(m) tile grid: each XCD owns a
    // 6(n) x 8(m) chunk (A 2MB + B 3MB ~ L2-resident).
    const int lin  = blockIdx.x + 12 * blockIdx.y;  // 0..383
    const int xcd  = lin & 7;
    const int slot = lin >> 3;                      // 0..47
    const int cxi  = xcd & 1, cyi = xcd >> 1;       // 2(n) x 4(m) chunks
    const int sx   = slot % 6, sy = slot / 6;       // 6 x 8
    const int n0   = (cxi * 6 + sx) * 256;
    const int m0   = (cyi * 8 + sy) * 128;

    const int wr = (wv >> 2) * 64;      // 0,64      (2 m-waves)
    const int wc = (wv & 3) * 64;       // 0..192    (4 n-waves)

    floatx4 acc[4][4];
    #pragma unroll
    for (int a = 0; a < 4; a++)
        #pragma unroll
        for (int bq = 0; bq < 4; bq++)
            acc[a][bq] = floatx4{0.f, 0.f, 0.f, 0.f};

    // pre-swizzled source chunk: c_src = (t&3) ^ ((row>>1)&3), row = t>>2
    const int gsw = ((tid & 3) ^ ((tid >> 3) & 3)) * 8;
    const ushort* ga  = hbf   + (size_t)(m0 + (tid >> 2)) * 1024 + gsw;
    const ushort* gb0 = wqkvT + (size_t)(n0 + (tid >> 2)) * 1024 + gsw;
    const ushort* gb1 = gb0 + (size_t)128 * 1024;   // rows +128: same XOR field
    const int wofs = wv * 512;          // wave-uniform LDS base (ushorts)

    auto stage = [&](int t, int ao, int bo) {
        const int k0 = t * 32;
        gload16(ga  + k0, &Al[ao + wofs]);
        gload16(gb0 + k0, &Bl[bo + wofs]);
        gload16(gb1 + k0, &Bl[bo + 4096 + wofs]);
    };

    int a0 = 0, a1 = 4096, a2 = 8192;
    int b0 = 0, b1 = 8192, b2 = 16384;
    stage(0, a0, b0);
    stage(1, a1, b1);
    asm volatile("s_waitcnt vmcnt(3)" ::: "memory");   // tile 0 resident
    __builtin_amdgcn_s_barrier();

    for (int it = 0; it < 32; it++) {
        const bool pre = (it + 2 < 32);
        if (pre) stage(it + 2, a2, b2);
        short8 af[4], bfr[4];
        #pragma unroll
        for (int fm = 0; fm < 4; fm++) {
            const int ra = wr + fm * 16 + l15;
            af[fm] = *(const short8*)&Al[a0 + ((ra * 32 + g * 8) ^ (((ra >> 1) & 3) << 3))];
        }
        #pragma unroll
        for (int fn = 0; fn < 4; fn++) {
            const int rb = wc + fn * 16 + l15;
            bfr[fn] = *(const short8*)&Bl[b0 + ((rb * 32 + g * 8) ^ (((rb >> 1) & 3) << 3))];
        }
        #pragma unroll
        for (int fm = 0; fm < 4; fm++)
            #pragma unroll
            for (int fn = 0; fn < 4; fn++)
                acc[fm][fn] = mfma_bf16(af[fm], bfr[fn], acc[fm][fn]);
        // complete only tile it+1 (oldest 3 loads); tile it+2 stays in flight
        if (pre) asm volatile("s_waitcnt vmcnt(3)" ::: "memory");
        else     asm volatile("s_waitcnt vmcnt(0)" ::: "memory");
        __builtin_amdgcn_s_barrier();
        int t0 = a0; a0 = a1; a1 = a2; a2 = t0;
        int t1 = b0; b0 = b1; b1 = b2; b2 = t1;
    }

    // epilogue: per-wave output rows m0+wr+fm*16+g*4+r, cols n0+wc+fn*16+l15
    #pragma unroll
    for (int fn = 0; fn < 4; fn++) {
        const int c    = n0 + wc + fn * 16 + l15;
        const int mp   = c / 384;
        const int rem  = c - mp * 384;
        const int tsel = rem >> 7;                    // 0=q 1=k 2=v
        const int j    = (rem >> 6) & 1;
        const int d    = rem & 63;
        const int head = mp * 2 + j;
        ushort* basep = (tsel == 0) ? Qb : (tsel == 1) ? Kb : Vb;
        const bool rope = (tsel < 2) && (d < ROT);
        // Q carries 1/sqrt(64) * log2(e) so attention uses exp2 directly
        const float qscale = (tsel == 0) ? 0.18033688011112042f : 1.0f;
        float freq = 0.f;
        if (rope) {
            freq = exp2f((float)(d >> 1) * -0.830482023721841f);
        }
        #pragma unroll
        for (int fm = 0; fm < 4; fm++) {
            #pragma unroll
            for (int r = 0; r < 4; r++) {
                int row = m0 + wr + fm * 16 + g * 4 + r;
                int bb  = row >> 11;
                int s   = row & 2047;
                float val = acc[fm][fn][r];
                float pv  = __shfl_xor(val, 1, 64);
                float outv = val;
                if (rope) {
                    float ang = (float)s * freq;
                    float sn, cs;
                    __sincosf(ang, &sn, &cs);
                    outv = ((d & 1) == 0) ? (val * cs - pv * sn)
                                          : (val * cs + pv * sn);
                }
                outv *= qscale;
                size_t off;
                if (tsel == 2)
                    off = ((size_t)(bb * NHEADS + head) * HDIM + d) * SEQ + s;
                else
                    off = ((size_t)(bb * NHEADS + head) * SEQ + s) * HDIM + d;
                basep[off] = f2bf(outv);
            }
        }
    }
}

// ---------------------------------------------------------------------------
// Kernel 2: flash attention, causal. 512 threads = 8 waves x 16 q-rows
// (Q tile 128), KV tiles 64. Complementary-qb pairing; 2-deep register
// prefetch + LDS double-buffer; exp2-domain softmax with per-lane defer-max
// (cross-lane reduces only on rescale) and epilogue-deferred l-sum.
// ---------------------------------------------------------------------------
__global__ __launch_bounds__(512, 4) void attn_kernel(
    const ushort* __restrict__ Qb, const ushort* __restrict__ Kb,
    const ushort* __restrict__ Vb, ushort* __restrict__ attn)
{
    __shared__ ushort Kl[2][64 * 72];      // [key][d], stride 72
    __shared__ ushort Vt[2][64 * 72];      // [d][key], stride 72

    const int tid  = threadIdx.x;
    const int lane = tid & 63;
    const int wv   = tid >> 6;             // 0..7
    const int g    = lane >> 4;
    const int l15  = lane & 15;

    const int l    = blockIdx.x + 16 * blockIdx.y + 256 * blockIdx.z;
    const int half = l >> 8;
    const int xx   = l & 15;
    const int hh   = (l >> 4) & 15;
    const int qb   = half ? xx : 15 - xx;
    const int bb   = half;

    const int q0 = qb * 128;
    const int wq = wv * 16;
    const size_t kvbase = (size_t)(bb * NHEADS + hh) * SEQ * HDIM;

    const int srow = tid >> 3;             // 0..63 staging row
    const int sch  = (tid & 7) * 8;        // staging col (ushort)

    short8 qreg[2];
    #pragma unroll
    for (int ks = 0; ks < 2; ks++)
        qreg[ks] = *(const short8*)(Qb + kvbase +
            (size_t)(q0 + wq + l15) * HDIM + ks * 32 + g * 8);

    float m = -__builtin_inff();
    float lsum = 0.f;                      // per-lane partial (16 keys/row)
    floatx4 of[4];
    #pragma unroll
    for (int df = 0; df < 4; df++) of[df] = floatx4{0.f, 0.f, 0.f, 0.f};

    const int nt = 2 * qb + 2;             // always even

    auto load_tile = [&](int tt, short8& kr, short8& vr) {
        const int kv = tt * 64;
        kr = *(const short8*)(Kb + kvbase + (size_t)(kv + srow) * HDIM + sch);
        vr = *(const short8*)(Vb + kvbase + (size_t)srow * SEQ + kv + sch);
    };
    auto write_tile = [&](int buf, short8& kr, short8& vr) {
        *(short8*)&Kl[buf][srow * 72 + sch] = kr;
        *(short8*)&Vt[buf][srow * 72 + sch] = vr;
    };
    auto compute_tile = [&](int t, const ushort* Kc, const ushort* Vc) {
        const int kv0 = t * 64;
        if (kv0 > q0 + wq + 15) return;    // fully-masked for this wave
        // QK^T (swapped): sf[kf], lane l15 = q-row, key = kv0 + kf*16 + g*4 + r
        floatx4 sf[4];
        __builtin_amdgcn_s_setprio(1);
        #pragma unroll
        for (int kf = 0; kf < 4; kf++) {
            short8 kr0 = *(const short8*)&Kc[(kf * 16 + l15) * 72 + g * 8];
            short8 kr1 = *(const short8*)&Kc[(kf * 16 + l15) * 72 + 32 + g * 8];
            floatx4 s = floatx4{0.f, 0.f, 0.f, 0.f};
            s = mfma_bf16(kr0, qreg[0], s);
            s = mfma_bf16(kr1, qreg[1], s);
            sf[kf] = s;
        }
        __builtin_amdgcn_s_setprio(0);

        const bool diag = (kv0 + 63 > q0 + wq);   // wave-uniform
        const int qg = q0 + wq + l15;
        float tmax = -__builtin_inff();
        if (diag) {
            #pragma unroll
            for (int kf = 0; kf < 4; kf++) {
                #pragma unroll
                for (int r = 0; r < 4; r++) {
                    int key = kv0 + kf * 16 + g * 4 + r;
                    float x = sf[kf][r];
                    if (key > qg) x = -1e9f;
                    sf[kf][r] = x;
                    tmax = fmaxf(tmax, x);
                }
            }
        } else {
            #pragma unroll
            for (int kf = 0; kf < 4; kf++)
                #pragma unroll
                for (int r = 0; r < 4; r++)
                    tmax = fmaxf(tmax, sf[kf][r]);
        }
        // per-lane defer-max: no cross-lane traffic in the common case
        if (!__all(tmax <= m + 8.0f)) {
            tmax = fmaxf(tmax, __shfl_xor(tmax, 16, 64));
            tmax = fmaxf(tmax, __shfl_xor(tmax, 32, 64));
            float mn = fmaxf(m, tmax);
            float f  = fexp2(m - mn);
            m = mn;
            lsum *= f;
            #pragma unroll
            for (int r = 0; r < 4; r++) {
                float fr = __shfl(f, g * 4 + r, 64);
                #pragma unroll
                for (int df = 0; df < 4; df++)
                    of[df][r] *= fr;
            }
        }
        float rs = 0.f;
        #pragma unroll
        for (int kf = 0; kf < 4; kf++) {
            #pragma unroll
            for (int r = 0; r < 4; r++) {
                float p = fexp2(sf[kf][r] - m);
                sf[kf][r] = p;
                rs += p;
            }
        }
        lsum += rs;
        // pack P into lane-local A-frags via v_cvt_pk_bf16_f32
        short8 pa[2];
        #pragma unroll
        for (int ks = 0; ks < 2; ks++) {
            union { short8 s; uint u[4]; } pu;
            #pragma unroll
            for (int w = 0; w < 4; w++) {
                const int kf = 2 * ks + (w >> 1);
                float lo = sf[kf][(w & 1) * 2 + 0];
                float hi = sf[kf][(w & 1) * 2 + 1];
                asm("v_cvt_pk_bf16_f32 %0, %1, %2"
                    : "=v"(pu.u[w]) : "v"(lo), "v"(hi));
            }
            pa[ks] = pu.s;
        }
        // PV
        __builtin_amdgcn_s_setprio(1);
        #pragma unroll
        for (int df = 0; df < 4; df++) {
            #pragma unroll
            for (int ks = 0; ks < 2; ks++) {
                const int vb = (df * 16 + l15) * 72 + ks * 32 + g * 4;
                uint2 v0 = *(const uint2*)&Vc[vb];
                uint2 v1 = *(const uint2*)&Vc[vb + 16];
                union { short8 s; uint4 u; } vv;
                vv.u.x = v0.x; vv.u.y = v0.y; vv.u.z = v1.x; vv.u.w = v1.y;
                of[df] = mfma_bf16(pa[ks], vv.s, of[df]);
            }
        }
        __builtin_amdgcn_s_setprio(0);
    };

    short8 kA, vA, kB, vB;
    load_tile(0, kA, vA);
    if (nt > 1) load_tile(1, kB, vB);
    write_tile(0, kA, vA);
    __syncthreads();

    for (int t = 0; t < nt; t += 2) {
        if (t + 2 < nt) load_tile(t + 2, kA, vA);
        compute_tile(t, Kl[0], Vt[0]);
        write_tile(1, kB, vB);
        __syncthreads();
        if (t + 3 < nt) load_tile(t + 3, kB, vB);
        compute_tile(t + 1, Kl[1], Vt[1]);
        if (t + 2 < nt) write_tile(0, kA, vA);
        __syncthreads();
    }

    // epilogue: reduce l across g-lanes once, O /= l, store attn (b,s,H) bf16
    lsum += __shfl_xor(lsum, 16, 64);
    lsum += __shfl_xor(lsum, 32, 64);
    #pragma unroll
    for (int r = 0; r < 4; r++) {
        float lr = __shfl(lsum, g * 4 + r, 64);
        float inv = 1.0f / lr;
        int q = q0 + wq + g * 4 + r;
        #pragma unroll
        for (int df = 0; df < 4; df++)
            attn[((size_t)bb * SEQ + q) * HID + hh * 64 + df * 16 + l15] =
                f2bf(of[df][r] * inv);
    }
}

// ---------------------------------------------------------------------------
// Kernel 3: out = attn @ w_out (M=4096, N=1024, K=1024), T4 depth-2
// counted-vmcnt pipeline (3 buffers, vmcnt(4) steady state) + T2 swizzle.
// ---------------------------------------------------------------------------
__global__ __launch_bounds__(256) void out_proj_kernel(
    const ushort* __restrict__ attn,    // (4096,1024) bf16
    const ushort* __restrict__ woutT,   // (1024,1024) bf16 (N,K)
    float* __restrict__ out)
{
    __shared__ ushort Al[3 * 4096];
    __shared__ ushort Bl[3 * 4096];
    const int tid  = threadIdx.x;
    const int lane = tid & 63;
    const int wv   = tid >> 6;
    const int g    = lane >> 4;
    const int l15  = lane & 15;

    const int lin  = blockIdx.x + 8 * blockIdx.y;   // 0..255
    const int xcd  = lin & 7;
    const int slot = lin >> 3;                      // 0..31
    const int cxi  = xcd & 1, cyi = xcd >> 1;
    const int sx   = slot & 3, sy = slot >> 2;      // 4x8
    const int n0   = (cxi * 4 + sx) * 128;
    const int m0   = (cyi * 8 + sy) * 128;

    const int wr = (wv >> 1) * 64;
    const int wc = (wv & 1) * 64;
    const int rowl = lane >> 2;
    // pre-swizzled source chunk: rows wv*32+rowl and +16 share the XOR field
    const int kcol = ((lane & 3) ^ ((lane >> 3) & 3)) * 8;

    floatx4 acc[4][4];
    #pragma unroll
    for (int a = 0; a < 4; a++)
        #pragma unroll
        for (int bq = 0; bq < 4; bq++)
            acc[a][bq] = floatx4{0.f, 0.f, 0.f, 0.f};

    const ushort* ga = attn  + (size_t)(m0 + wv * 32 + rowl) * 1024 + kcol;
    const ushort* gb = woutT + (size_t)(n0 + wv * 32 + rowl) * 1024 + kcol;
    const int lofs = wv * 1024;

    auto stage = [&](int t, int ao, int bo) {
        const int k0 = t * 32;
        gload16(ga + k0,             &Al[ao + lofs]);
        gload16(ga + k0 + 16 * 1024, &Al[ao + lofs + 512]);
        gload16(gb + k0,             &Bl[bo + lofs]);
        gload16(gb + k0 + 16 * 1024, &Bl[bo + lofs + 512]);
    };

    int a0 = 0, a1 = 4096, a2 = 8192;
    int b0 = 0, b1 = 4096, b2 = 8192;
    stage(0, a0, b0);
    stage(1, a1, b1);
    asm volatile("s_waitcnt vmcnt(4)" ::: "memory");
    __builtin_amdgcn_s_barrier();

    for (int it = 0; it < 32; it++) {
        const bool pre = (it + 2 < 32);
        if (pre) stage(it + 2, a2, b2);
        short8 af[4], bfr[4];
        #pragma unroll
        for (int fm = 0; fm < 4; fm++) {
            const int ra = wr + fm * 16 + l15;
            af[fm] = *(const short8*)&Al[a0 + ((ra * 32 + g * 8) ^ (((ra >> 1) & 3) << 3))];
        }
        #pragma unroll
        for (int fn = 0; fn < 4; fn++) {
            const int rb = wc + fn * 16 + l15;
            bfr[fn] = *(const short8*)&Bl[b0 + ((rb * 32 + g * 8) ^ (((rb >> 1) & 3) << 3))];
        }
        #pragma unroll
        for (int fm = 0; fm < 4; fm++)
            #pragma unroll
            for (int fn = 0; fn < 4; fn++)
                acc[fm][fn] = mfma_bf16(af[fm], bfr[fn], acc[fm][fn]);
        if (pre) asm volatile("s_waitcnt vmcnt(4)" ::: "memory");
        else     asm volatile("s_waitcnt vmcnt(0)" ::: "memory");
        __builtin_amdgcn_s_barrier();
        int t0 = a0; a0 = a1; a1 = a2; a2 = t0;
        int t1 = b0; b0 = b1; b1 = b2; b2 = t1;
    }
    #pragma unroll
    for (int fm = 0; fm < 4; fm++)
        #pragma unroll
        for (int fn = 0; fn < 4; fn++)
            #pragma unroll
            for (int r = 0; r < 4; r++) {
                int row = m0 + wr + fm * 16 + g * 4 + r;
                int col = n0 + wc + fn * 16 + l15;
                out[(size_t)row * 1024 + col] = acc[fm][fn][r];
            }
}

// ---------------------------------------------------------------------------
extern "C" void kernel_launch(void* const* d_in, const int* in_sizes, int n_in,
                              void* d_out, int out_size, void* d_ws, size_t ws_size,
                              hipStream_t stream)
{
    const float* hidden = (const float*)d_in[0];
    const float* wqkv   = (const float*)d_in[1];
    const float* wout   = (const float*)d_in[2];
    float* out = (float*)d_out;

    const size_t NELEM = (size_t)2 * SEQ * HID;   // 4,194,304
    ushort* Qb    = (ushort*)d_ws;
    ushort* Kb    = Qb + NELEM;
    ushort* Vb    = Kb + NELEM;
    ushort* hbf   = Vb + NELEM;                   // hidden bf16; later reused as attn
    ushort* wqkvT = hbf + NELEM;                  // 3072*1024
    ushort* woutT = wqkvT + (size_t)3072 * 1024;  // 1024*1024
    ushort* attnb = hbf;                          // alias: lifetime disjoint

    convert_bf16_kernel<<<2048, 256, 0, stream>>>(hidden, hbf, (int)NELEM);
    transpose_bf16_kernel<<<dim3(48, 16), 256, 0, stream>>>(wqkv, wqkvT, 1024, 3072);
    transpose_bf16_kernel<<<dim3(16, 16), 256, 0, stream>>>(wout, woutT, 1024, 1024);
    qkv_rope_kernel<<<dim3(12, 32), 512, 0, stream>>>(hbf, wqkvT, Qb, Kb, Vb);
    attn_kernel<<<dim3(16, NHEADS, 2), 512, 0, stream>>>(Qb, Kb, Vb, attnb);
    out_proj_kernel<<<dim3(8, 32), 256, 0, stream>>>(attnb, woutT, out);
}

// Round 17
// 126.149 us; speedup vs baseline: 1.1450x; 1.0045x over previous
//
#include <hip/hip_runtime.h>

#define SEQ   2048
#define NHEADS 16
#define HDIM  64
#define HID   1024
#define ROT   32

typedef __attribute__((ext_vector_type(8))) short  short8;
typedef __attribute__((ext_vector_type(4))) float  floatx4;

__device__ __forceinline__ ushort f2bf(float f) {
    union { float f; uint u; } v; v.f = f;
    uint x = v.u;
    uint r = (x + 0x7FFFu + ((x >> 16) & 1u)) >> 16;
    return (ushort)r;
}

__device__ __forceinline__ float fexp2(float x) {
    return __builtin_amdgcn_exp2f(x);     // v_exp_f32 directly
}

__device__ __forceinline__ floatx4 mfma_bf16(short8 a, short8 b, floatx4 c) {
    return __builtin_amdgcn_mfma_f32_16x16x32_bf16(a, b, c, 0, 0, 0);
}

__device__ __forceinline__ void gload16(const ushort* g, ushort* l) {
    __builtin_amdgcn_global_load_lds(
        (const __attribute__((address_space(1))) void*)g,
        (__attribute__((address_space(3))) void*)l, 16, 0, 0);
}

// ---------------------------------------------------------------------------
// Fused pre-pass: convert hidden fp32->bf16 (blocks 0..2047),
// transpose-convert wqkv (blocks 2048..2815), wout (blocks 2816..3071).
// Branch is block-uniform so the __syncthreads in the transpose is safe.
// ---------------------------------------------------------------------------
__device__ __forceinline__ void transpose_tile(
    const float* __restrict__ src, ushort* __restrict__ dst,
    int K, int N, int k0, int n0, int tid, ushort* Tl)
{
    #pragma unroll
    for (int i = 0; i < 4; i++) {
        int lin = tid + 256 * i;
        int row = lin >> 4;
        int c4  = (lin & 15) * 4;
        float4 v = *(const float4*)(src + (size_t)(k0 + row) * N + n0 + c4);
        uint2 u;
        u.x = (uint)f2bf(v.x) | ((uint)f2bf(v.y) << 16);
        u.y = (uint)f2bf(v.z) | ((uint)f2bf(v.w) << 16);
        *(uint2*)&Tl[row * 68 + c4] = u;
    }
    __syncthreads();
    #pragma unroll
    for (int j = 0; j < 2; j++) {
        int lin = tid + 256 * j;
        int n = lin >> 3, c = lin & 7;
        short8 v;
        #pragma unroll
        for (int u = 0; u < 8; u++) v[u] = (short)Tl[(c * 8 + u) * 68 + n];
        *(short8*)(dst + (size_t)(n0 + n) * K + k0 + c * 8) = v;
    }
}

__global__ __launch_bounds__(256) void prepass_kernel(
    const float* __restrict__ hidden, const float* __restrict__ wqkv,
    const float* __restrict__ wout, ushort* __restrict__ hbf,
    ushort* __restrict__ wqkvT, ushort* __restrict__ woutT)
{
    __shared__ ushort Tl[64 * 68];
    const int bid = blockIdx.x;
    const int tid = threadIdx.x;
    if (bid < 2048) {
        int i = (bid * 256 + tid) * 8;
        float4 a = *(const float4*)(hidden + i);
        float4 b = *(const float4*)(hidden + i + 4);
        short8 v;
        v[0] = (short)f2bf(a.x); v[1] = (short)f2bf(a.y);
        v[2] = (short)f2bf(a.z); v[3] = (short)f2bf(a.w);
        v[4] = (short)f2bf(b.x); v[5] = (short)f2bf(b.y);
        v[6] = (short)f2bf(b.z); v[7] = (short)f2bf(b.w);
        *(short8*)(hbf + i) = v;
    } else if (bid < 2048 + 768) {
        const int lin = bid - 2048;
        transpose_tile(wqkv, wqkvT, 1024, 3072,
                       (lin / 48) * 64, (lin % 48) * 64, tid, Tl);
    } else {
        const int lin = bid - 2816;
        transpose_tile(wout, woutT, 1024, 1024,
                       (lin / 16) * 64, (lin % 16) * 64, tid, Tl);
    }
}

// ---------------------------------------------------------------------------
// Kernel 1: qkv = hidden @ w_qkv (M=4096, N=3072, K=1024) bf16 inputs.
// 128(M) x 256(N) tile, 8 waves, T4 depth-2 counted-vmcnt pipeline +
// T2 both-sides swizzle (r16 state — structure exhausted at ~50us).
// Fused RoPE + head split. Q pre-scaled by 0.125*log2(e).
// Q,K (b,h,s,d); V (b,h,d,s).
// ---------------------------------------------------------------------------
__global__ __launch_bounds__(512) void qkv_rope_kernel(
    const ushort* __restrict__ hbf,     // (4096,1024) bf16
    const ushort* __restrict__ wqkvT,   // (3072,1024) bf16 (N,K)
    ushort* __restrict__ Qb, ushort* __restrict__ Kb, ushort* __restrict__ Vb)
{
    __shared__ ushort Al[3 * 4096];
    __shared__ ushort Bl[3 * 8192];
    const int tid  = threadIdx.x;
    const int lane = tid & 63;
    const int wv   = tid >> 6;
    const int g    = lane >> 4;
    const int l15  = lane & 15;

    const int lin  = blockIdx.x + 12 * blockIdx.y;  // 0..383
    const int xcd  = lin & 7;
    const int slot = lin >> 3;
    const int cxi  = xcd & 1, cyi = xcd >> 1;
    const int sx   = slot % 6, sy = slot / 6;
    const int n0   = (cxi * 6 + sx) * 256;
    const int m0   = (cyi * 8 + sy) * 128;

    const int wr = (wv >> 2) * 64;
    const int wc = (wv & 3) * 64;

    floatx4 acc[4][4];
    #pragma unroll
    for (int a = 0; a < 4; a++)
        #pragma unroll
        for (int bq = 0; bq < 4; bq++)
            acc[a][bq] = floatx4{0.f, 0.f, 0.f, 0.f};

    const int gsw = ((tid & 3) ^ ((tid >> 3) & 3)) * 8;
    const ushort* ga  = hbf   + (size_t)(m0 + (tid >> 2)) * 1024 + gsw;
    const ushort* gb0 = wqkvT + (size_t)(n0 + (tid >> 2)) * 1024 + gsw;
    const ushort* gb1 = gb0 + (size_t)128 * 1024;
    const int wofs = wv * 512;

    auto stage = [&](int t, int ao, int bo) {
        const int k0 = t * 32;
        gload16(ga  + k0, &Al[ao + wofs]);
        gload16(gb0 + k0, &Bl[bo + wofs]);
        gload16(gb1 + k0, &Bl[bo + 4096 + wofs]);
    };

    int a0 = 0, a1 = 4096, a2 = 8192;
    int b0 = 0, b1 = 8192, b2 = 16384;
    stage(0, a0, b0);
    stage(1, a1, b1);
    asm volatile("s_waitcnt vmcnt(3)" ::: "memory");
    __builtin_amdgcn_s_barrier();

    for (int it = 0; it < 32; it++) {
        const bool pre = (it + 2 < 32);
        if (pre) stage(it + 2, a2, b2);
        short8 af[4], bfr[4];
        #pragma unroll
        for (int fm = 0; fm < 4; fm++) {
            const int ra = wr + fm * 16 + l15;
            af[fm] = *(const short8*)&Al[a0 + ((ra * 32 + g * 8) ^ (((ra >> 1) & 3) << 3))];
        }
        #pragma unroll
        for (int fn = 0; fn < 4; fn++) {
            const int rb = wc + fn * 16 + l15;
            bfr[fn] = *(const short8*)&Bl[b0 + ((rb * 32 + g * 8) ^ (((rb >> 1) & 3) << 3))];
        }
        #pragma unroll
        for (int fm = 0; fm < 4; fm++)
            #pragma unroll
            for (int fn = 0; fn < 4; fn++)
                acc[fm][fn] = mfma_bf16(af[fm], bfr[fn], acc[fm][fn]);
        if (pre) asm volatile("s_waitcnt vmcnt(3)" ::: "memory");
        else     asm volatile("s_waitcnt vmcnt(0)" ::: "memory");
        __builtin_amdgcn_s_barrier();
        int t0 = a0; a0 = a1; a1 = a2; a2 = t0;
        int t1 = b0; b0 = b1; b1 = b2; b2 = t1;
    }

    #pragma unroll
    for (int fn = 0; fn < 4; fn++) {
        const int c    = n0 + wc + fn * 16 + l15;
        const int mp   = c / 384;
        const int rem  = c - mp * 384;
        const int tsel = rem >> 7;                    // 0=q 1=k 2=v
        const int j    = (rem >> 6) & 1;
        const int d    = rem & 63;
        const int head = mp * 2 + j;
        ushort* basep = (tsel == 0) ? Qb : (tsel == 1) ? Kb : Vb;
        const bool rope = (tsel < 2) && (d < ROT);
        const float qscale = (tsel == 0) ? 0.18033688011112042f : 1.0f;
        float freq = 0.f;
        if (rope) {
            freq = exp2f((float)(d >> 1) * -0.830482023721841f);
        }
        #pragma unroll
        for (int fm = 0; fm < 4; fm++) {
            #pragma unroll
            for (int r = 0; r < 4; r++) {
                int row = m0 + wr + fm * 16 + g * 4 + r;
                int bb  = row >> 11;
                int s   = row & 2047;
                float val = acc[fm][fn][r];
                float pv  = __shfl_xor(val, 1, 64);
                float outv = val;
                if (rope) {
                    float ang = (float)s * freq;
                    float sn, cs;
                    __sincosf(ang, &sn, &cs);
                    outv = ((d & 1) == 0) ? (val * cs - pv * sn)
                                          : (val * cs + pv * sn);
                }
                outv *= qscale;
                size_t off;
                if (tsel == 2)
                    off = ((size_t)(bb * NHEADS + head) * HDIM + d) * SEQ + s;
                else
                    off = ((size_t)(bb * NHEADS + head) * SEQ + s) * HDIM + d;
                basep[off] = f2bf(outv);
            }
        }
    }
}

// ---------------------------------------------------------------------------
// Kernel 2: flash attention, causal. 512 threads = 8 waves x 16 q-rows,
// KV tiles 64. NEW: K/V staged via global_load_lds into linear [64][64]
// LDS with both-sides XOR swizzle (chunk ^= row&7 on source AND read) —
// eliminates the reg-stage write phase + 32 staging VGPRs; 2-phase
// pipeline (stage t+1, compute t, vmcnt(0)+barrier). Complementary-qb
// pairing; exp2-domain softmax with per-lane defer-max; deferred l-sum.
// ---------------------------------------------------------------------------
__global__ __launch_bounds__(512, 4) void attn_kernel(
    const ushort* __restrict__ Qb, const ushort* __restrict__ Kb,
    const ushort* __restrict__ Vb, ushort* __restrict__ attn)
{
    __shared__ ushort Kl[2][64 * 64];      // [key][d], linear, source-swizzled
    __shared__ ushort Vt[2][64 * 64];      // [d][key], linear, source-swizzled

    const int tid  = threadIdx.x;
    const int lane = tid & 63;
    const int wv   = tid >> 6;             // 0..7
    const int g    = lane >> 4;
    const int l15  = lane & 15;

    const int l    = blockIdx.x + 16 * blockIdx.y + 256 * blockIdx.z;
    const int half = l >> 8;
    const int xx   = l & 15;
    const int hh   = (l >> 4) & 15;
    const int qb   = half ? xx : 15 - xx;
    const int bb   = half;

    const int q0 = qb * 128;
    const int wq = wv * 16;
    const size_t kvbase = (size_t)(bb * NHEADS + hh) * SEQ * HDIM;

    const int srow = tid >> 3;             // 0..63 staging row
    const int scsw = ((tid & 7) ^ (srow & 7)) * 8;   // swizzled source chunk
    const int wofs = wv * 512;             // per-wave LDS dest base (ushort)

    short8 qreg[2];
    #pragma unroll
    for (int ks = 0; ks < 2; ks++)
        qreg[ks] = *(const short8*)(Qb + kvbase +
            (size_t)(q0 + wq + l15) * HDIM + ks * 32 + g * 8);

    float m = -__builtin_inff();
    float lsum = 0.f;                      // per-lane partial (16 keys/row)
    floatx4 of[4];
    #pragma unroll
    for (int df = 0; df < 4; df++) of[df] = floatx4{0.f, 0.f, 0.f, 0.f};

    const int nt = 2 * qb + 2;

    auto stage = [&](int tt, int buf) {
        const int kv = tt * 64;
        gload16(Kb + kvbase + (size_t)(kv + srow) * HDIM + scsw, &Kl[buf][wofs]);
        gload16(Vb + kvbase + (size_t)srow * SEQ + kv + scsw,   &Vt[buf][wofs]);
    };

    auto compute_tile = [&](int t, const ushort* Kc, const ushort* Vc) {
        const int kv0 = t * 64;
        if (kv0 > q0 + wq + 15) return;    // fully-masked for this wave
        // QK^T (swapped): lane l15 = q-row, key = kv0 + kf*16 + g*4 + r
        floatx4 sf[4];
        __builtin_amdgcn_s_setprio(1);
        #pragma unroll
        for (int kf = 0; kf < 4; kf++) {
            const int key = kf * 16 + l15;
            const int rb  = key * 64;
            const int sw  = key & 7;
            short8 kr0 = *(const short8*)&Kc[rb + ((g ^ sw) << 3)];
            short8 kr1 = *(const short8*)&Kc[rb + (((g + 4) ^ sw) << 3)];
            floatx4 s = floatx4{0.f, 0.f, 0.f, 0.f};
            s = mfma_bf16(kr0, qreg[0], s);
            s = mfma_bf16(kr1, qreg[1], s);
            sf[kf] = s;
        }
        __builtin_amdgcn_s_setprio(0);

        const bool diag = (kv0 + 63 > q0 + wq);   // wave-uniform
        const int qg = q0 + wq + l15;
        float tmax = -__builtin_inff();
        if (diag) {
            #pragma unroll
            for (int kf = 0; kf < 4; kf++) {
                #pragma unroll
                for (int r = 0; r < 4; r++) {
                    int key = kv0 + kf * 16 + g * 4 + r;
                    float x = sf[kf][r];
                    if (key > qg) x = -1e9f;
                    sf[kf][r] = x;
                    tmax = fmaxf(tmax, x);
                }
            }
        } else {
            #pragma unroll
            for (int kf = 0; kf < 4; kf++)
                #pragma unroll
                for (int r = 0; r < 4; r++)
                    tmax = fmaxf(tmax, sf[kf][r]);
        }
        if (!__all(tmax <= m + 8.0f)) {
            tmax = fmaxf(tmax, __shfl_xor(tmax, 16, 64));
            tmax = fmaxf(tmax, __shfl_xor(tmax, 32, 64));
            float mn = fmaxf(m, tmax);
            float f  = fexp2(m - mn);
            m = mn;
            lsum *= f;
            #pragma unroll
            for (int r = 0; r < 4; r++) {
                float fr = __shfl(f, g * 4 + r, 64);
                #pragma unroll
                for (int df = 0; df < 4; df++)
                    of[df][r] *= fr;
            }
        }
        float rs = 0.f;
        #pragma unroll
        for (int kf = 0; kf < 4; kf++) {
            #pragma unroll
            for (int r = 0; r < 4; r++) {
                float p = fexp2(sf[kf][r] - m);
                sf[kf][r] = p;
                rs += p;
            }
        }
        lsum += rs;
        // pack P into lane-local A-frags via v_cvt_pk_bf16_f32
        short8 pa[2];
        #pragma unroll
        for (int ks = 0; ks < 2; ks++) {
            union { short8 s; uint u[4]; } pu;
            #pragma unroll
            for (int w = 0; w < 4; w++) {
                const int kf = 2 * ks + (w >> 1);
                float lo = sf[kf][(w & 1) * 2 + 0];
                float hi = sf[kf][(w & 1) * 2 + 1];
                asm("v_cvt_pk_bf16_f32 %0, %1, %2"
                    : "=v"(pu.u[w]) : "v"(lo), "v"(hi));
            }
            pa[ks] = pu.s;
        }
        // PV: B-frag elem j reads Vt[d][ks*32 + 16*(j>>2) + g*4 + (j&3)]
        __builtin_amdgcn_s_setprio(1);
        #pragma unroll
        for (int df = 0; df < 4; df++) {
            const int d  = df * 16 + l15;
            const int rb = d * 64;
            const int sw = d & 7;
            #pragma unroll
            for (int ks = 0; ks < 2; ks++) {
                const int c0 = ks * 4 + (g >> 1);
                uint2 v0 = *(const uint2*)&Vc[rb + ((c0 ^ sw) << 3) + (g & 1) * 4];
                uint2 v1 = *(const uint2*)&Vc[rb + (((c0 + 2) ^ sw) << 3) + (g & 1) * 4];
                union { short8 s; uint4 u; } vv;
                vv.u.x = v0.x; vv.u.y = v0.y; vv.u.z = v1.x; vv.u.w = v1.y;
                of[df] = mfma_bf16(pa[ks], vv.s, of[df]);
            }
        }
        __builtin_amdgcn_s_setprio(0);
    };

    stage(0, 0);
    asm volatile("s_waitcnt vmcnt(0)" ::: "memory");
    __builtin_amdgcn_s_barrier();

    int cur = 0;
    for (int t = 0; t < nt; t++) {
        if (t + 1 < nt) stage(t + 1, cur ^ 1);
        compute_tile(t, Kl[cur], Vt[cur]);
        asm volatile("s_waitcnt vmcnt(0)" ::: "memory");
        __builtin_amdgcn_s_barrier();
        cur ^= 1;
    }

    // epilogue: reduce l across g-lanes once, O /= l, store attn (b,s,H) bf16
    lsum += __shfl_xor(lsum, 16, 64);
    lsum += __shfl_xor(lsum, 32, 64);
    #pragma unroll
    for (int r = 0; r < 4; r++) {
        float lr = __shfl(lsum, g * 4 + r, 64);
        float inv = 1.0f / lr;
        int q = q0 + wq + g * 4 + r;
        #pragma unroll
        for (int df = 0; df < 4; df++)
            attn[((size_t)bb * SEQ + q) * HID + hh * 64 + df * 16 + l15] =
                f2bf(of[df][r] * inv);
    }
}

// ---------------------------------------------------------------------------
// Kernel 3: out = attn @ w_out (M=4096, N=1024, K=1024), T4 depth-2
// counted-vmcnt pipeline (3 buffers, vmcnt(4) steady state) + T2 swizzle.
// ---------------------------------------------------------------------------
__global__ __launch_bounds__(256) void out_proj_kernel(
    const ushort* __restrict__ attn,    // (4096,1024) bf16
    const ushort* __restrict__ woutT,   // (1024,1024) bf16 (N,K)
    float* __restrict__ out)
{
    __shared__ ushort Al[3 * 4096];
    __shared__ ushort Bl[3 * 4096];
    const int tid  = threadIdx.x;
    const int lane = tid & 63;
    const int wv   = tid >> 6;
    const int g    = lane >> 4;
    const int l15  = lane & 15;

    const int lin  = blockIdx.x + 8 * blockIdx.y;   // 0..255
    const int xcd  = lin & 7;
    const int slot = lin >> 3;
    const int cxi  = xcd & 1, cyi = xcd >> 1;
    const int sx   = slot & 3, sy = slot >> 2;
    const int n0   = (cxi * 4 + sx) * 128;
    const int m0   = (cyi * 8 + sy) * 128;

    const int wr = (wv >> 1) * 64;
    const int wc = (wv & 1) * 64;
    const int rowl = lane >> 2;
    const int kcol = ((lane & 3) ^ ((lane >> 3) & 3)) * 8;

    floatx4 acc[4][4];
    #pragma unroll
    for (int a = 0; a < 4; a++)
        #pragma unroll
        for (int bq = 0; bq < 4; bq++)
            acc[a][bq] = floatx4{0.f, 0.f, 0.f, 0.f};

    const ushort* ga = attn  + (size_t)(m0 + wv * 32 + rowl) * 1024 + kcol;
    const ushort* gb = woutT + (size_t)(n0 + wv * 32 + rowl) * 1024 + kcol;
    const int lofs = wv * 1024;

    auto stage = [&](int t, int ao, int bo) {
        const int k0 = t * 32;
        gload16(ga + k0,             &Al[ao + lofs]);
        gload16(ga + k0 + 16 * 1024, &Al[ao + lofs + 512]);
        gload16(gb + k0,             &Bl[bo + lofs]);
        gload16(gb + k0 + 16 * 1024, &Bl[bo + lofs + 512]);
    };

    int a0 = 0, a1 = 4096, a2 = 8192;
    int b0 = 0, b1 = 4096, b2 = 8192;
    stage(0, a0, b0);
    stage(1, a1, b1);
    asm volatile("s_waitcnt vmcnt(4)" ::: "memory");
    __builtin_amdgcn_s_barrier();

    for (int it = 0; it < 32; it++) {
        const bool pre = (it + 2 < 32);
        if (pre) stage(it + 2, a2, b2);
        short8 af[4], bfr[4];
        #pragma unroll
        for (int fm = 0; fm < 4; fm++) {
            const int ra = wr + fm * 16 + l15;
            af[fm] = *(const short8*)&Al[a0 + ((ra * 32 + g * 8) ^ (((ra >> 1) & 3) << 3))];
        }
        #pragma unroll
        for (int fn = 0; fn < 4; fn++) {
            const int rb = wc + fn * 16 + l15;
            bfr[fn] = *(const short8*)&Bl[b0 + ((rb * 32 + g * 8) ^ (((rb >> 1) & 3) << 3))];
        }
        #pragma unroll
        for (int fm = 0; fm < 4; fm++)
            #pragma unroll
            for (int fn = 0; fn < 4; fn++)
                acc[fm][fn] = mfma_bf16(af[fm], bfr[fn], acc[fm][fn]);
        if (pre) asm volatile("s_waitcnt vmcnt(4)" ::: "memory");
        else     asm volatile("s_waitcnt vmcnt(0)" ::: "memory");
        __builtin_amdgcn_s_barrier();
        int t0 = a0; a0 = a1; a1 = a2; a2 = t0;
        int t1 = b0; b0 = b1; b1 = b2; b2 = t1;
    }
    #pragma unroll
    for (int fm = 0; fm < 4; fm++)
        #pragma unroll
        for (int fn = 0; fn < 4; fn++)
            #pragma unroll
            for (int r = 0; r < 4; r++) {
                int row = m0 + wr + fm * 16 + g * 4 + r;
                int col = n0 + wc + fn * 16 + l15;
                out[(size_t)row * 1024 + col] = acc[fm][fn][r];
            }
}

// ---------------------------------------------------------------------------
extern "C" void kernel_launch(void* const* d_in, const int* in_sizes, int n_in,
                              void* d_out, int out_size, void* d_ws, size_t ws_size,
                              hipStream_t stream)
{
    const float* hidden = (const float*)d_in[0];
    const float* wqkv   = (const float*)d_in[1];
    const float* wout   = (const float*)d_in[2];
    float* out = (float*)d_out;

    const size_t NELEM = (size_t)2 * SEQ * HID;   // 4,194,304
    ushort* Qb    = (ushort*)d_ws;
    ushort* Kb    = Qb + NELEM;
    ushort* Vb    = Kb + NELEM;
    ushort* hbf   = Vb + NELEM;                   // hidden bf16; later reused as attn
    ushort* wqkvT = hbf + NELEM;                  // 3072*1024
    ushort* woutT = wqkvT + (size_t)3072 * 1024;  // 1024*1024
    ushort* attnb = hbf;                          // alias: lifetime disjoint

    prepass_kernel<<<3072, 256, 0, stream>>>(hidden, wqkv, wout, hbf, wqkvT, woutT);
    qkv_rope_kernel<<<dim3(12, 32), 512, 0, stream>>>(hbf, wqkvT, Qb, Kb, Vb);
    attn_kernel<<<dim3(16, NHEADS, 2), 512, 0, stream>>>(Qb, Kb, Vb, attnb);
    out_proj_kernel<<<dim3(8, 32), 256, 0, stream>>>(attnb, woutT, out);
}

// Round 18
// 120.471 us; speedup vs baseline: 1.1990x; 1.0471x over previous
//
#include <hip/hip_runtime.h>

#define SEQ   2048
#define NHEADS 16
#define HDIM  64
#define HID   1024
#define ROT   32

typedef __attribute__((ext_vector_type(8))) short  short8;
typedef __attribute__((ext_vector_type(4))) float  floatx4;

__device__ __forceinline__ ushort f2bf(float f) {
    union { float f; uint u; } v; v.f = f;
    uint x = v.u;
    uint r = (x + 0x7FFFu + ((x >> 16) & 1u)) >> 16;
    return (ushort)r;
}

__device__ __forceinline__ float fexp2(float x) {
    return __builtin_amdgcn_exp2f(x);     // v_exp_f32 directly
}

__device__ __forceinline__ floatx4 mfma_bf16(short8 a, short8 b, floatx4 c) {
    return __builtin_amdgcn_mfma_f32_16x16x32_bf16(a, b, c, 0, 0, 0);
}

__device__ __forceinline__ void gload16(const ushort* g, ushort* l) {
    __builtin_amdgcn_global_load_lds(
        (const __attribute__((address_space(1))) void*)g,
        (__attribute__((address_space(3))) void*)l, 16, 0, 0);
}

// ---------------------------------------------------------------------------
// Fused pre-pass: convert hidden fp32->bf16 (blocks 0..2047),
// transpose-convert wqkv (blocks 2048..2815), wout (blocks 2816..3071).
// ---------------------------------------------------------------------------
__device__ __forceinline__ void transpose_tile(
    const float* __restrict__ src, ushort* __restrict__ dst,
    int K, int N, int k0, int n0, int tid, ushort* Tl)
{
    #pragma unroll
    for (int i = 0; i < 4; i++) {
        int lin = tid + 256 * i;
        int row = lin >> 4;
        int c4  = (lin & 15) * 4;
        float4 v = *(const float4*)(src + (size_t)(k0 + row) * N + n0 + c4);
        uint2 u;
        u.x = (uint)f2bf(v.x) | ((uint)f2bf(v.y) << 16);
        u.y = (uint)f2bf(v.z) | ((uint)f2bf(v.w) << 16);
        *(uint2*)&Tl[row * 68 + c4] = u;
    }
    __syncthreads();
    #pragma unroll
    for (int j = 0; j < 2; j++) {
        int lin = tid + 256 * j;
        int n = lin >> 3, c = lin & 7;
        short8 v;
        #pragma unroll
        for (int u = 0; u < 8; u++) v[u] = (short)Tl[(c * 8 + u) * 68 + n];
        *(short8*)(dst + (size_t)(n0 + n) * K + k0 + c * 8) = v;
    }
}

__global__ __launch_bounds__(256) void prepass_kernel(
    const float* __restrict__ hidden, const float* __restrict__ wqkv,
    const float* __restrict__ wout, ushort* __restrict__ hbf,
    ushort* __restrict__ wqkvT, ushort* __restrict__ woutT)
{
    __shared__ ushort Tl[64 * 68];
    const int bid = blockIdx.x;
    const int tid = threadIdx.x;
    if (bid < 2048) {
        int i = (bid * 256 + tid) * 8;
        float4 a = *(const float4*)(hidden + i);
        float4 b = *(const float4*)(hidden + i + 4);
        short8 v;
        v[0] = (short)f2bf(a.x); v[1] = (short)f2bf(a.y);
        v[2] = (short)f2bf(a.z); v[3] = (short)f2bf(a.w);
        v[4] = (short)f2bf(b.x); v[5] = (short)f2bf(b.y);
        v[6] = (short)f2bf(b.z); v[7] = (short)f2bf(b.w);
        *(short8*)(hbf + i) = v;
    } else if (bid < 2048 + 768) {
        const int lin = bid - 2048;
        transpose_tile(wqkv, wqkvT, 1024, 3072,
                       (lin / 48) * 64, (lin % 48) * 64, tid, Tl);
    } else {
        const int lin = bid - 2816;
        transpose_tile(wout, woutT, 1024, 1024,
                       (lin / 16) * 64, (lin % 16) * 64, tid, Tl);
    }
}

// ---------------------------------------------------------------------------
// Kernel 1: qkv = hidden @ w_qkv (M=4096, N=3072, K=1024) bf16 inputs.
// 128(M) x 256(N) tile, 8 waves, T4 depth-2 counted-vmcnt + T2 swizzle
// (frozen at r16 state — 2-phase-family structure saturated ~50us).
// Fused RoPE + head split. Q pre-scaled by 0.125*log2(e).
// Q,K (b,h,s,d); V (b,h,d,s).
// ---------------------------------------------------------------------------
__global__ __launch_bounds__(512) void qkv_rope_kernel(
    const ushort* __restrict__ hbf,     // (4096,1024) bf16
    const ushort* __restrict__ wqkvT,   // (3072,1024) bf16 (N,K)
    ushort* __restrict__ Qb, ushort* __restrict__ Kb, ushort* __restrict__ Vb)
{
    __shared__ ushort Al[3 * 4096];
    __shared__ ushort Bl[3 * 8192];
    const int tid  = threadIdx.x;
    const int lane = tid & 63;
    const int wv   = tid >> 6;
    const int g    = lane >> 4;
    const int l15  = lane & 15;

    const int lin  = blockIdx.x + 12 * blockIdx.y;  // 0..383
    const int xcd  = lin & 7;
    const int slot = lin >> 3;
    const int cxi  = xcd & 1, cyi = xcd >> 1;
    const int sx   = slot % 6, sy = slot / 6;
    const int n0   = (cxi * 6 + sx) * 256;
    const int m0   = (cyi * 8 + sy) * 128;

    const int wr = (wv >> 2) * 64;
    const int wc = (wv & 3) * 64;

    floatx4 acc[4][4];
    #pragma unroll
    for (int a = 0; a < 4; a++)
        #pragma unroll
        for (int bq = 0; bq < 4; bq++)
            acc[a][bq] = floatx4{0.f, 0.f, 0.f, 0.f};

    const int gsw = ((tid & 3) ^ ((tid >> 3) & 3)) * 8;
    const ushort* ga  = hbf   + (size_t)(m0 + (tid >> 2)) * 1024 + gsw;
    const ushort* gb0 = wqkvT + (size_t)(n0 + (tid >> 2)) * 1024 + gsw;
    const ushort* gb1 = gb0 + (size_t)128 * 1024;
    const int wofs = wv * 512;

    auto stage = [&](int t, int ao, int bo) {
        const int k0 = t * 32;
        gload16(ga  + k0, &Al[ao + wofs]);
        gload16(gb0 + k0, &Bl[bo + wofs]);
        gload16(gb1 + k0, &Bl[bo + 4096 + wofs]);
    };

    int a0 = 0, a1 = 4096, a2 = 8192;
    int b0 = 0, b1 = 8192, b2 = 16384;
    stage(0, a0, b0);
    stage(1, a1, b1);
    asm volatile("s_waitcnt vmcnt(3)" ::: "memory");
    __builtin_amdgcn_s_barrier();

    for (int it = 0; it < 32; it++) {
        const bool pre = (it + 2 < 32);
        if (pre) stage(it + 2, a2, b2);
        short8 af[4], bfr[4];
        #pragma unroll
        for (int fm = 0; fm < 4; fm++) {
            const int ra = wr + fm * 16 + l15;
            af[fm] = *(const short8*)&Al[a0 + ((ra * 32 + g * 8) ^ (((ra >> 1) & 3) << 3))];
        }
        #pragma unroll
        for (int fn = 0; fn < 4; fn++) {
            const int rb = wc + fn * 16 + l15;
            bfr[fn] = *(const short8*)&Bl[b0 + ((rb * 32 + g * 8) ^ (((rb >> 1) & 3) << 3))];
        }
        #pragma unroll
        for (int fm = 0; fm < 4; fm++)
            #pragma unroll
            for (int fn = 0; fn < 4; fn++)
                acc[fm][fn] = mfma_bf16(af[fm], bfr[fn], acc[fm][fn]);
        if (pre) asm volatile("s_waitcnt vmcnt(3)" ::: "memory");
        else     asm volatile("s_waitcnt vmcnt(0)" ::: "memory");
        __builtin_amdgcn_s_barrier();
        int t0 = a0; a0 = a1; a1 = a2; a2 = t0;
        int t1 = b0; b0 = b1; b1 = b2; b2 = t1;
    }

    #pragma unroll
    for (int fn = 0; fn < 4; fn++) {
        const int c    = n0 + wc + fn * 16 + l15;
        const int mp   = c / 384;
        const int rem  = c - mp * 384;
        const int tsel = rem >> 7;                    // 0=q 1=k 2=v
        const int j    = (rem >> 6) & 1;
        const int d    = rem & 63;
        const int head = mp * 2 + j;
        ushort* basep = (tsel == 0) ? Qb : (tsel == 1) ? Kb : Vb;
        const bool rope = (tsel < 2) && (d < ROT);
        const float qscale = (tsel == 0) ? 0.18033688011112042f : 1.0f;
        float freq = 0.f;
        if (rope) {
            freq = exp2f((float)(d >> 1) * -0.830482023721841f);
        }
        #pragma unroll
        for (int fm = 0; fm < 4; fm++) {
            #pragma unroll
            for (int r = 0; r < 4; r++) {
                int row = m0 + wr + fm * 16 + g * 4 + r;
                int bb  = row >> 11;
                int s   = row & 2047;
                float val = acc[fm][fn][r];
                float pv  = __shfl_xor(val, 1, 64);
                float outv = val;
                if (rope) {
                    float ang = (float)s * freq;
                    float sn, cs;
                    __sincosf(ang, &sn, &cs);
                    outv = ((d & 1) == 0) ? (val * cs - pv * sn)
                                          : (val * cs + pv * sn);
                }
                outv *= qscale;
                size_t off;
                if (tsel == 2)
                    off = ((size_t)(bb * NHEADS + head) * HDIM + d) * SEQ + s;
                else
                    off = ((size_t)(bb * NHEADS + head) * SEQ + s) * HDIM + d;
                basep[off] = f2bf(outv);
            }
        }
    }
}

// ---------------------------------------------------------------------------
// Kernel 2: flash attention, causal. 512 threads = 8 waves x 16 q-rows,
// KV tiles **128** (was 64): halves barrier/drain/fixed-cost count, doubles
// MFMA per barrier window (32/wave). K/V staged via global_load_lds, linear
// LDS + both-sides XOR swizzle (K: chunk^=row&7 of 8; V: chunk^=d&15 of 16,
// stage/read sides derived consistent; all fragment reads 2-way = free).
// 2-phase pipeline; complementary-qb pairing (pairs sum to 17 tiles/CU);
// exp2-domain softmax, per-lane defer-max, deferred l-sum.
// ---------------------------------------------------------------------------
__global__ __launch_bounds__(512, 4) void attn_kernel(
    const ushort* __restrict__ Qb, const ushort* __restrict__ Kb,
    const ushort* __restrict__ Vb, ushort* __restrict__ attn)
{
    __shared__ ushort Kl[2][128 * 64];     // [key][d]
    __shared__ ushort Vt[2][64 * 128];     // [d][key]

    const int tid  = threadIdx.x;
    const int lane = tid & 63;
    const int wv   = tid >> 6;             // 0..7
    const int g    = lane >> 4;
    const int l15  = lane & 15;

    const int l    = blockIdx.x + 16 * blockIdx.y + 256 * blockIdx.z;
    const int half = l >> 8;
    const int xx   = l & 15;
    const int hh   = (l >> 4) & 15;
    const int qb   = half ? xx : 15 - xx;
    const int bb   = half;

    const int q0 = qb * 128;
    const int wq = wv * 16;
    const size_t kvbase = (size_t)(bb * NHEADS + hh) * SEQ * HDIM;

    // --- staging geometry (gload_lds: dest = wave-uniform base + lane*16) ---
    // K tile: 128 rows x 8 chunks(16B). call j: chunk ci=(wv+8j)*64+lane ->
    //   row=(wv+8j)*8+(lane>>3), c=lane&7, src chunk = c ^ (lane>>3).
    const int krow0 = wv * 8 + (lane >> 3);          // rows for j=0; +64 for j=1
    const int kcsw  = ((lane & 7) ^ (lane >> 3)) * 8;
    // V tile: 64 rows x 16 chunks. call j: row=(wv+8j)*4+(lane>>4), c=lane&15,
    //   sw = row&15 = (wv&3)*4+(lane>>4) (j-invariant), src chunk = c ^ sw.
    const int vrow0 = wv * 4 + (lane >> 4);          // rows for j=0; +32 for j=1
    const int vsw   = (wv & 3) * 4 + (lane >> 4);
    const int vcsw  = ((lane & 15) ^ vsw) * 8;

    short8 qreg[2];
    #pragma unroll
    for (int ks = 0; ks < 2; ks++)
        qreg[ks] = *(const short8*)(Qb + kvbase +
            (size_t)(q0 + wq + l15) * HDIM + ks * 32 + g * 8);

    float m = -__builtin_inff();
    float lsum = 0.f;                      // per-lane partial (32 keys/row)
    floatx4 of[4];
    #pragma unroll
    for (int df = 0; df < 4; df++) of[df] = floatx4{0.f, 0.f, 0.f, 0.f};

    const int nt = qb + 1;                 // KV tiles of 128

    auto stage = [&](int tt, int buf) {
        const int kv = tt * 128;
        gload16(Kb + kvbase + (size_t)(kv + krow0) * HDIM + kcsw,
                &Kl[buf][wv * 512]);
        gload16(Kb + kvbase + (size_t)(kv + krow0 + 64) * HDIM + kcsw,
                &Kl[buf][(wv + 8) * 512]);
        gload16(Vb + kvbase + (size_t)vrow0 * SEQ + kv + vcsw,
                &Vt[buf][wv * 512]);
        gload16(Vb + kvbase + (size_t)(vrow0 + 32) * SEQ + kv + vcsw,
                &Vt[buf][(wv + 8) * 512]);
    };

    auto compute_tile = [&](int t, const ushort* Kc, const ushort* Vc) {
        const int kv0 = t * 128;
        if (kv0 > q0 + wq + 15) return;    // fully-masked for this wave
        // QK^T (swapped): lane l15 = q-row, key = kv0 + kf*16 + g*4 + r
        floatx4 sf[8];
        __builtin_amdgcn_s_setprio(1);
        #pragma unroll
        for (int kf = 0; kf < 8; kf++) {
            const int key = kf * 16 + l15;
            const int rb  = key * 64;
            const int sw  = key & 7;
            short8 kr0 = *(const short8*)&Kc[rb + ((g ^ sw) << 3)];
            short8 kr1 = *(const short8*)&Kc[rb + (((g + 4) ^ sw) << 3)];
            floatx4 s = floatx4{0.f, 0.f, 0.f, 0.f};
            s = mfma_bf16(kr0, qreg[0], s);
            s = mfma_bf16(kr1, qreg[1], s);
            sf[kf] = s;
        }
        __builtin_amdgcn_s_setprio(0);

        const bool diag = (kv0 + 127 > q0 + wq);   // wave-uniform
        const int qg = q0 + wq + l15;
        float tmax = -__builtin_inff();
        if (diag) {
            #pragma unroll
            for (int kf = 0; kf < 8; kf++) {
                #pragma unroll
                for (int r = 0; r < 4; r++) {
                    int key = kv0 + kf * 16 + g * 4 + r;
                    float x = sf[kf][r];
                    if (key > qg) x = -1e9f;
                    sf[kf][r] = x;
                    tmax = fmaxf(tmax, x);
                }
            }
        } else {
            #pragma unroll
            for (int kf = 0; kf < 8; kf++)
                #pragma unroll
                for (int r = 0; r < 4; r++)
                    tmax = fmaxf(tmax, sf[kf][r]);
        }
        if (!__all(tmax <= m + 8.0f)) {
            tmax = fmaxf(tmax, __shfl_xor(tmax, 16, 64));
            tmax = fmaxf(tmax, __shfl_xor(tmax, 32, 64));
            float mn = fmaxf(m, tmax);
            float f  = fexp2(m - mn);
            m = mn;
            lsum *= f;
            #pragma unroll
            for (int r = 0; r < 4; r++) {
                float fr = __shfl(f, g * 4 + r, 64);
                #pragma unroll
                for (int df = 0; df < 4; df++)
                    of[df][r] *= fr;
            }
        }
        float rs = 0.f;
        #pragma unroll
        for (int kf = 0; kf < 8; kf++) {
            #pragma unroll
            for (int r = 0; r < 4; r++) {
                float p = fexp2(sf[kf][r] - m);
                sf[kf][r] = p;
                rs += p;
            }
        }
        lsum += rs;
        // pack P into lane-local A-frags: pa[ks] elem j = sf[2ks+(j>>2)][j&3]
        short8 pa[4];
        #pragma unroll
        for (int ks = 0; ks < 4; ks++) {
            union { short8 s; uint u[4]; } pu;
            #pragma unroll
            for (int w = 0; w < 4; w++) {
                const int kf = 2 * ks + (w >> 1);
                float lo = sf[kf][(w & 1) * 2 + 0];
                float hi = sf[kf][(w & 1) * 2 + 1];
                asm("v_cvt_pk_bf16_f32 %0, %1, %2"
                    : "=v"(pu.u[w]) : "v"(lo), "v"(hi));
            }
            pa[ks] = pu.s;
        }
        // PV: B-frag elem j reads Vt[d][ks*32 + 16*(j>>2) + g*4 + (j&3)]
        __builtin_amdgcn_s_setprio(1);
        #pragma unroll
        for (int df = 0; df < 4; df++) {
            const int d  = df * 16 + l15;
            const int rb = d * 128;
            const int sw = l15;            // d & 15
            #pragma unroll
            for (int ks = 0; ks < 4; ks++) {
                const int c0 = ks * 4 + (g >> 1);
                uint2 v0 = *(const uint2*)&Vc[rb + ((c0 ^ sw) << 3) + (g & 1) * 4];
                uint2 v1 = *(const uint2*)&Vc[rb + (((c0 + 2) ^ sw) << 3) + (g & 1) * 4];
                union { short8 s; uint4 u; } vv;
                vv.u.x = v0.x; vv.u.y = v0.y; vv.u.z = v1.x; vv.u.w = v1.y;
                of[df] = mfma_bf16(pa[ks], vv.s, of[df]);
            }
        }
        __builtin_amdgcn_s_setprio(0);
    };

    stage(0, 0);
    asm volatile("s_waitcnt vmcnt(0)" ::: "memory");
    __builtin_amdgcn_s_barrier();

    int cur = 0;
    for (int t = 0; t < nt; t++) {
        if (t + 1 < nt) stage(t + 1, cur ^ 1);
        compute_tile(t, Kl[cur], Vt[cur]);
        asm volatile("s_waitcnt vmcnt(0)" ::: "memory");
        __builtin_amdgcn_s_barrier();
        cur ^= 1;
    }

    // epilogue: reduce l across g-lanes once, O /= l, store attn (b,s,H) bf16
    lsum += __shfl_xor(lsum, 16, 64);
    lsum += __shfl_xor(lsum, 32, 64);
    #pragma unroll
    for (int r = 0; r < 4; r++) {
        float lr = __shfl(lsum, g * 4 + r, 64);
        float inv = 1.0f / lr;
        int q = q0 + wq + g * 4 + r;
        #pragma unroll
        for (int df = 0; df < 4; df++)
            attn[((size_t)bb * SEQ + q) * HID + hh * 64 + df * 16 + l15] =
                f2bf(of[df][r] * inv);
    }
}

// ---------------------------------------------------------------------------
// Kernel 3: out = attn @ w_out (M=4096, N=1024, K=1024), T4 depth-2
// counted-vmcnt pipeline (3 buffers, vmcnt(4) steady state) + T2 swizzle.
// ---------------------------------------------------------------------------
__global__ __launch_bounds__(256) void out_proj_kernel(
    const ushort* __restrict__ attn,    // (4096,1024) bf16
    const ushort* __restrict__ woutT,   // (1024,1024) bf16 (N,K)
    float* __restrict__ out)
{
    __shared__ ushort Al[3 * 4096];
    __shared__ ushort Bl[3 * 4096];
    const int tid  = threadIdx.x;
    const int lane = tid & 63;
    const int wv   = tid >> 6;
    const int g    = lane >> 4;
    const int l15  = lane & 15;

    const int lin  = blockIdx.x + 8 * blockIdx.y;   // 0..255
    const int xcd  = lin & 7;
    const int slot = lin >> 3;
    const int cxi  = xcd & 1, cyi = xcd >> 1;
    const int sx   = slot & 3, sy = slot >> 2;
    const int n0   = (cxi * 4 + sx) * 128;
    const int m0   = (cyi * 8 + sy) * 128;

    const int wr = (wv >> 1) * 64;
    const int wc = (wv & 1) * 64;
    const int rowl = lane >> 2;
    const int kcol = ((lane & 3) ^ ((lane >> 3) & 3)) * 8;

    floatx4 acc[4][4];
    #pragma unroll
    for (int a = 0; a < 4; a++)
        #pragma unroll
        for (int bq = 0; bq < 4; bq++)
            acc[a][bq] = floatx4{0.f, 0.f, 0.f, 0.f};

    const ushort* ga = attn  + (size_t)(m0 + wv * 32 + rowl) * 1024 + kcol;
    const ushort* gb = woutT + (size_t)(n0 + wv * 32 + rowl) * 1024 + kcol;
    const int lofs = wv * 1024;

    auto stage = [&](int t, int ao, int bo) {
        const int k0 = t * 32;
        gload16(ga + k0,             &Al[ao + lofs]);
        gload16(ga + k0 + 16 * 1024, &Al[ao + lofs + 512]);
        gload16(gb + k0,             &Bl[bo + lofs]);
        gload16(gb + k0 + 16 * 1024, &Bl[bo + lofs + 512]);
    };

    int a0 = 0, a1 = 4096, a2 = 8192;
    int b0 = 0, b1 = 4096, b2 = 8192;
    stage(0, a0, b0);
    stage(1, a1, b1);
    asm volatile("s_waitcnt vmcnt(4)" ::: "memory");
    __builtin_amdgcn_s_barrier();

    for (int it = 0; it < 32; it++) {
        const bool pre = (it + 2 < 32);
        if (pre) stage(it + 2, a2, b2);
        short8 af[4], bfr[4];
        #pragma unroll
        for (int fm = 0; fm < 4; fm++) {
            const int ra = wr + fm * 16 + l15;
            af[fm] = *(const short8*)&Al[a0 + ((ra * 32 + g * 8) ^ (((ra >> 1) & 3) << 3))];
        }
        #pragma unroll
        for (int fn = 0; fn < 4; fn++) {
            const int rb = wc + fn * 16 + l15;
            bfr[fn] = *(const short8*)&Bl[b0 + ((rb * 32 + g * 8) ^ (((rb >> 1) & 3) << 3))];
        }
        #pragma unroll
        for (int fm = 0; fm < 4; fm++)
            #pragma unroll
            for (int fn = 0; fn < 4; fn++)
                acc[fm][fn] = mfma_bf16(af[fm], bfr[fn], acc[fm][fn]);
        if (pre) asm volatile("s_waitcnt vmcnt(4)" ::: "memory");
        else     asm volatile("s_waitcnt vmcnt(0)" ::: "memory");
        __builtin_amdgcn_s_barrier();
        int t0 = a0; a0 = a1; a1 = a2; a2 = t0;
        int t1 = b0; b0 = b1; b1 = b2; b2 = t1;
    }
    #pragma unroll
    for (int fm = 0; fm < 4; fm++)
        #pragma unroll
        for (int fn = 0; fn < 4; fn++)
            #pragma unroll
            for (int r = 0; r < 4; r++) {
                int row = m0 + wr + fm * 16 + g * 4 + r;
                int col = n0 + wc + fn * 16 + l15;
                out[(size_t)row * 1024 + col] = acc[fm][fn][r];
            }
}

// ---------------------------------------------------------------------------
extern "C" void kernel_launch(void* const* d_in, const int* in_sizes, int n_in,
                              void* d_out, int out_size, void* d_ws, size_t ws_size,
                              hipStream_t stream)
{
    const float* hidden = (const float*)d_in[0];
    const float* wqkv   = (const float*)d_in[1];
    const float* wout   = (const float*)d_in[2];
    float* out = (float*)d_out;

    const size_t NELEM = (size_t)2 * SEQ * HID;   // 4,194,304
    ushort* Qb    = (ushort*)d_ws;
    ushort* Kb    = Qb + NELEM;
    ushort* Vb    = Kb + NELEM;
    ushort* hbf   = Vb + NELEM;                   // hidden bf16; later reused as attn
    ushort* wqkvT = hbf + NELEM;                  // 3072*1024
    ushort* woutT = wqkvT + (size_t)3072 * 1024;  // 1024*1024
    ushort* attnb = hbf;                          // alias: lifetime disjoint

    prepass_kernel<<<3072, 256, 0, stream>>>(hidden, wqkv, wout, hbf, wqkvT, woutT);
    qkv_rope_kernel<<<dim3(12, 32), 512, 0, stream>>>(hbf, wqkvT, Qb, Kb, Vb);
    attn_kernel<<<dim3(16, NHEADS, 2), 512, 0, stream>>>(Qb, Kb, Vb, attnb);
    out_proj_kernel<<<dim3(8, 32), 256, 0, stream>>>(attnb, woutT, out);
}